// Round 5
// baseline (478.221 us; speedup 1.0000x reference)
//
#include <hip/hip_runtime.h>

#define TPB 256
#define CSH 10                 // nodes per dst bucket = 1024
#define CN 1024
#define NBC_MAX 128
#define STILE 4096             // bscat tile (16 KB stage -> 8 blocks/CU)
#define EPT (STILE / TPB)      // 16

// fixed-point packing: value -> (int)rn(v*SCALE) + BIAS, two per u64
#define B20 1048576            // bias 2^20
#define S1F 131072.0f          // layer-1 scale 2^17
#define S2F 8192.0f            // layer-2 scale 2^13

typedef unsigned long long u64;

__device__ __forceinline__ unsigned enc_fx(float v, float scale) {
    int xi = __float2int_rn(v * scale);
    xi = max(-(B20 - 1), min(B20 - 1, xi));
    return (unsigned)(xi + B20);
}

__global__ void k_zero(int* __restrict__ p, int n) {
    int i = blockIdx.x * blockDim.x + threadIdx.x;
    if (i < n) p[i] = 0;
}

// degrees via fire-and-forget global atomics (L2-resident 400 KB table).
// Isolated on purpose: its duration measures the gfx950 global-atomic rate.
__global__ void k_degg_v(const int* __restrict__ dst, int* __restrict__ deg, int E4) {
    int i = blockIdx.x * blockDim.x + threadIdx.x;
    if (i >= E4) return;
    int4 d4 = ((const int4*)dst)[i];
    atomicAdd(&deg[d4.x], 1);
    atomicAdd(&deg[d4.y], 1);
    atomicAdd(&deg[d4.z], 1);
    atomicAdd(&deg[d4.w], 1);
}
__global__ void k_degg_s(const int* __restrict__ dst, int* __restrict__ deg, int E) {
    int stride = gridDim.x * blockDim.x;
    for (int i = blockIdx.x * blockDim.x + threadIdx.x; i < E; i += stride)
        atomicAdd(&deg[dst[i]], 1);
}

// bucket edge-counts from deg: bsize[b] = sum of deg over the bucket's nodes
__global__ void k_bsum(const int* __restrict__ deg, int* __restrict__ bsize, int N) {
    __shared__ int red[TPB];
    int b = blockIdx.x;
    int v0 = b << CSH;
    int sum = 0;
    for (int i = threadIdx.x; i < CN; i += TPB) {
        int v = v0 + i;
        if (v < N) sum += deg[v];
    }
    red[threadIdx.x] = sum;
    __syncthreads();
    for (int off = TPB / 2; off > 0; off >>= 1) {
        if (threadIdx.x < off) red[threadIdx.x] += red[threadIdx.x + off];
        __syncthreads();
    }
    if (threadIdx.x == 0) bsize[b] = red[0];
}

// exclusive scan of bucket sizes -> base[0..NBC]; also init bulk-reserve cursors
__global__ void k_scanbase(const int* __restrict__ bsize, int* __restrict__ base,
                           int* __restrict__ cur, int NBC) {
    __shared__ int s[NBC_MAX];
    int t = threadIdx.x;
    if (t < NBC_MAX) s[t] = (t < NBC) ? bsize[t] : 0;
    __syncthreads();
    for (int off = 1; off < NBC_MAX; off <<= 1) {
        int v = 0;
        if (t < NBC_MAX && t >= off) v = s[t - off];
        __syncthreads();
        if (t < NBC_MAX) s[t] += v;
        __syncthreads();
    }
    if (t < NBC) {
        int b = (t == 0) ? 0 : s[t - 1];
        base[t] = b;
        cur[t] = b;
    }
    if (t == 0) base[NBC] = s[NBC - 1];
}

// bucket scatter: in-LDS grouping by dst-bucket, per-bin BULK cursor reservation
// (98 low-contention atomics/block), wave-coalesced burst flush. Output: packed
// bucket-contiguous; intra-bucket order arbitrary (integer sums => bit-exact).
__global__ void k_bscat(const int* __restrict__ src, const int* __restrict__ dst,
                        int* __restrict__ cur, unsigned* __restrict__ packed,
                        int E, int NBC) {
    __shared__ unsigned stage[STILE];          // 16 KB
    __shared__ int cnt[NBC_MAX], lb[NBC_MAX], resv[NBC_MAX];
    int tb = blockIdx.x * STILE;
    int te = min(E, tb + STILE);
    if (threadIdx.x < NBC_MAX) cnt[threadIdx.x] = 0;
    __syncthreads();
    unsigned pk[EPT];
    int br[EPT];   // bucket | rank<<7  (bucket < 128)
#pragma unroll
    for (int u = 0; u < EPT; u++) {
        int i = tb + u * TPB + (int)threadIdx.x;
        br[u] = -1;
        if (i < te) {
            int d = dst[i];
            int b = d >> CSH;
            pk[u] = ((unsigned)src[i] << CSH) | (unsigned)(d & (CN - 1));
            int r = atomicAdd(&cnt[b], 1);     // rank doubles as count
            br[u] = b | (r << 7);
        }
    }
    __syncthreads();
    if (threadIdx.x < (unsigned)NBC) {
        int b = threadIdx.x;
        int sum = 0;
        for (int j = 0; j < b; j++) sum += cnt[j];   // same-addr broadcast reads
        lb[b] = sum;
        resv[b] = cnt[b] ? atomicAdd(&cur[b], cnt[b]) : 0;
    }
    __syncthreads();
#pragma unroll
    for (int u = 0; u < EPT; u++) {
        if (br[u] >= 0) {
            int b = br[u] & (NBC_MAX - 1);
            stage[lb[b] + (br[u] >> 7)] = pk[u];
        }
    }
    __syncthreads();
    int wv = threadIdx.x >> 6, lane = threadIdx.x & 63;
    for (int b = wv; b < NBC; b += 4) {        // burst flush, coalesced
        int c = cnt[b];
        if (!c) continue;
        int gb = resv[b], s0 = lb[b];
        for (int i = lane; i < c; i += 64)
            packed[gb + i] = stage[s0 + i];
    }
}

// xs = x * rsqrt(deg+1) (float4 self-term) and encoded uint4 for gathers
__global__ void k_prepv(const float* __restrict__ x, const int* __restrict__ deg,
                        float* __restrict__ xs, unsigned* __restrict__ xse, int N) {
    int v = blockIdx.x * blockDim.x + threadIdx.x;
    if (v >= N) return;
    float di = rsqrtf((float)(deg[v] + 1));
    float4 xv = ((const float4*)x)[v];
    xv.x *= di; xv.y *= di; xv.z *= di; xv.w *= di;
    ((float4*)xs)[v] = xv;
    uint4 e;
    e.x = enc_fx(xv.x, S1F); e.y = enc_fx(xv.y, S1F);
    e.z = enc_fx(xv.z, S1F); e.w = enc_fx(xv.w, S1F);
    ((uint4*)xse)[v] = e;
}

#define AGG1_AT(pkv, gv) { int n_ = (int)((pkv) & (CN - 1)) * 3; \
    atomicAdd(&acc[n_],     (u64)(gv).x | ((u64)(gv).y << 32)); \
    atomicAdd(&acc[n_ + 1], (u64)(gv).z | ((u64)(gv).w << 32)); }

// layer-1 edge pass over bucket-contiguous packed (unsorted within bucket):
// 8-deep clamped-load / predicated-atomic pipeline keeps ~8 gathers in flight
// per thread (R1 lesson: gathers are latency-bound, concurrency is the fix).
__global__ void k_agg1u(const unsigned* __restrict__ packed, const int* __restrict__ base,
                        const unsigned* __restrict__ xse, u64* __restrict__ partial1, int S1) {
    __shared__ u64 acc[CN * 3];   // stride 3 u64 to spread banks; 24 KB
    for (int i = threadIdx.x; i < CN * 3; i += TPB) acc[i] = 0ULL;
    __syncthreads();
    int b = blockIdx.x / S1, s = blockIdx.x - b * S1;
    int lo = base[b], sz = base[b + 1] - lo;
    int i0 = lo + (int)((long long)sz * s / S1);
    int i1 = lo + (int)((long long)sz * (s + 1) / S1);
    const uint4* xse4 = (const uint4*)xse;
    int iend = i1 - 1;
    for (int i = i0 + (int)threadIdx.x; i < i1; i += 8 * TPB) {
        unsigned p[8];
        uint4 g[8];
#pragma unroll
        for (int k = 0; k < 8; k++) {
            int idx = i + k * TPB;
            p[k] = packed[min(idx, iend)];     // clamped: always in-bucket
            g[k] = xse4[p[k] >> CSH];
        }
#pragma unroll
        for (int k = 0; k < 8; k++) {
            if (i + k * TPB < i1) AGG1_AT(p[k], g[k]);
        }
    }
    __syncthreads();
    u64* pp = partial1 + (size_t)blockIdx.x * (CN * 2);
    for (int i2 = threadIdx.x; i2 < CN * 2; i2 += TPB)
        pp[i2] = acc[(i2 >> 1) * 3 + (i2 & 1)];
}

// layer-1 combine: decode fixed-point, +self, *dis -> MLP -> hs2 (float + encoded)
__global__ void k_comb1q(const u64* __restrict__ partial1,
                         const float* __restrict__ xs, const int* __restrict__ deg,
                         const float* __restrict__ W1, const float* __restrict__ b1,
                         const float* __restrict__ W2,
                         float* __restrict__ hs2f, unsigned* __restrict__ hs2e,
                         int S1, int N) {
    __shared__ float w1[64], w2[32], bb[16];
    if (threadIdx.x < 64) w1[threadIdx.x] = W1[threadIdx.x];
    if (threadIdx.x < 32) w2[threadIdx.x] = W2[threadIdx.x];
    if (threadIdx.x < 16) bb[threadIdx.x] = b1[threadIdx.x];
    __syncthreads();
    int v = blockIdx.x * blockDim.x + threadIdx.x;
    if (v >= N) return;
    int b = v >> CSH, lv = v & (CN - 1);
    u64 a01 = 0, a23 = 0;
    for (int s = 0; s < S1; s++) {
        const u64* q = partial1 + ((size_t)(b * S1 + s) * CN + lv) * 2;
        a01 += q[0];
        a23 += q[1];
    }
    int dg = deg[v];
    long long bias = (long long)dg << 20;
    const float inv = 1.0f / S1F;
    float f0 = (float)((long long)(a01 & 0xffffffffULL) - bias) * inv;
    float f1 = (float)((long long)(a01 >> 32) - bias) * inv;
    float f2 = (float)((long long)(a23 & 0xffffffffULL) - bias) * inv;
    float f3 = (float)((long long)(a23 >> 32) - bias) * inv;
    float4 self = ((const float4*)xs)[v];
    float di = rsqrtf((float)(dg + 1));
    float v0 = (f0 + self.x) * di, v1 = (f1 + self.y) * di;
    float v2 = (f2 + self.z) * di, v3 = (f3 + self.w) * di;
    float s0 = 0.f, s1 = 0.f;
#pragma unroll
    for (int j = 0; j < 16; j++) {
        float h = v0 * w1[j] + v1 * w1[16 + j] + v2 * w1[32 + j] + v3 * w1[48 + j] + bb[j];
        h = fmaxf(h, 0.0f);
        s0 += h * w2[2 * j];
        s1 += h * w2[2 * j + 1];
    }
    s0 *= di; s1 *= di;
    ((float2*)hs2f)[v] = make_float2(s0, s1);
    uint2 e;
    e.x = enc_fx(s0, S2F);
    e.y = enc_fx(s1, S2F);
    ((uint2*)hs2e)[v] = e;
}

// layer-2 edge pass: same 8-deep pipeline, uint2 gathers, 1 u64 atomic/edge
__global__ void k_agg2u(const unsigned* __restrict__ packed, const int* __restrict__ base,
                        const unsigned* __restrict__ hs2e, u64* __restrict__ partial2, int S2) {
    __shared__ u64 acc[CN];   // 8 KB
    for (int i = threadIdx.x; i < CN; i += TPB) acc[i] = 0ULL;
    __syncthreads();
    int b = blockIdx.x / S2, s = blockIdx.x - b * S2;
    int lo = base[b], sz = base[b + 1] - lo;
    int i0 = lo + (int)((long long)sz * s / S2);
    int i1 = lo + (int)((long long)sz * (s + 1) / S2);
    const uint2* h2 = (const uint2*)hs2e;
    int iend = i1 - 1;
    for (int i = i0 + (int)threadIdx.x; i < i1; i += 8 * TPB) {
        unsigned p[8];
        uint2 g[8];
#pragma unroll
        for (int k = 0; k < 8; k++) {
            int idx = i + k * TPB;
            p[k] = packed[min(idx, iend)];
            g[k] = h2[p[k] >> CSH];
        }
#pragma unroll
        for (int k = 0; k < 8; k++) {
            if (i + k * TPB < i1)
                atomicAdd(&acc[p[k] & (CN - 1)], (u64)g[k].x | ((u64)g[k].y << 32));
        }
    }
    __syncthreads();
    u64* pp = partial2 + (size_t)blockIdx.x * CN;
    for (int i2 = threadIdx.x; i2 < CN; i2 += TPB) pp[i2] = acc[i2];
}

// layer-2 combine: decode, +self, *dis, +bias -> out
__global__ void k_comb2q(const u64* __restrict__ partial2,
                         const float* __restrict__ hs2f, const int* __restrict__ deg,
                         const float* __restrict__ b2, float* __restrict__ out,
                         int S2, int N) {
    int v = blockIdx.x * blockDim.x + threadIdx.x;
    if (v >= N) return;
    int b = v >> CSH, lv = v & (CN - 1);
    u64 t = 0;
    for (int s = 0; s < S2; s++)
        t += partial2[(size_t)(b * S2 + s) * CN + lv];
    int dg = deg[v];
    long long bias = (long long)dg << 20;
    const float inv = 1.0f / S2F;
    float f0 = (float)((long long)(t & 0xffffffffULL) - bias) * inv;
    float f1 = (float)((long long)(t >> 32) - bias) * inv;
    float2 self = ((const float2*)hs2f)[v];
    float di = rsqrtf((float)(dg + 1));
    ((float2*)out)[v] = make_float2((f0 + self.x) * di + b2[0],
                                    (f1 + self.y) * di + b2[1]);
}

// ---------------- fallback (R1 atomic pipeline) ----------------

__global__ void k_deg_fb(const int* __restrict__ dst, int* __restrict__ deg, int E) {
    int i = blockIdx.x * blockDim.x + threadIdx.x;
    if (i < E) atomicAdd(&deg[dst[i]], 1);
}
__global__ void k_dis_fb(const int* __restrict__ deg, float* __restrict__ dis, int N) {
    int v = blockIdx.x * blockDim.x + threadIdx.x;
    if (v < N) dis[v] = rsqrtf((float)(deg[v] + 1));
}
__global__ void k_lin1_fb(const float* __restrict__ x, const float* __restrict__ W1,
                          const float* __restrict__ dis, float* __restrict__ hs1,
                          float* __restrict__ agg1, int N) {
    __shared__ float w[64];
    if (threadIdx.x < 64) w[threadIdx.x] = W1[threadIdx.x];
    __syncthreads();
    int v = blockIdx.x * blockDim.x + threadIdx.x;
    if (v >= N) return;
    float4 xv = ((const float4*)x)[v];
    float d = dis[v];
#pragma unroll
    for (int j = 0; j < 16; j++) {
        float h = (xv.x * w[j] + xv.y * w[16 + j] + xv.z * w[32 + j] + xv.w * w[48 + j]) * d;
        hs1[v * 16 + j] = h;
        agg1[v * 16 + j] = h;
    }
}
__global__ void k_scat1_fb(const int* __restrict__ src, const int* __restrict__ dst,
                           const float* __restrict__ hs1, float* __restrict__ agg1, int E4) {
    int t = blockIdx.x * blockDim.x + threadIdx.x;
    if (t >= E4) return;
    int e = t >> 2, q = t & 3;
    int s = src[e], d = dst[e];
    float4 m = ((const float4*)hs1)[s * 4 + q];
    float* a = agg1 + (size_t)d * 16 + q * 4;
    atomicAdd(a + 0, m.x); atomicAdd(a + 1, m.y);
    atomicAdd(a + 2, m.z); atomicAdd(a + 3, m.w);
}
__global__ void k_lin2_fb(const float* __restrict__ agg1, const float* __restrict__ dis,
                          const float* __restrict__ b1, const float* __restrict__ W2,
                          float* __restrict__ hs2, float* __restrict__ agg2, int N) {
    __shared__ float w[32];
    __shared__ float bb[16];
    if (threadIdx.x < 32) w[threadIdx.x] = W2[threadIdx.x];
    if (threadIdx.x < 16) bb[threadIdx.x] = b1[threadIdx.x];
    __syncthreads();
    int v = blockIdx.x * blockDim.x + threadIdx.x;
    if (v >= N) return;
    float d = dis[v];
    float a0 = 0.f, a1 = 0.f;
#pragma unroll
    for (int k = 0; k < 16; k++) {
        float r = fmaxf(agg1[v * 16 + k] * d + bb[k], 0.0f);
        a0 += r * w[k * 2 + 0];
        a1 += r * w[k * 2 + 1];
    }
    float2 hv = make_float2(a0 * d, a1 * d);
    ((float2*)hs2)[v] = hv;
    ((float2*)agg2)[v] = hv;
}
__global__ void k_scat2_fb(const int* __restrict__ src, const int* __restrict__ dst,
                           const float* __restrict__ hs2, float* __restrict__ agg2, int E) {
    int e = blockIdx.x * blockDim.x + threadIdx.x;
    if (e >= E) return;
    int s = src[e], d = dst[e];
    float2 m = ((const float2*)hs2)[s];
    atomicAdd(&agg2[d * 2 + 0], m.x);
    atomicAdd(&agg2[d * 2 + 1], m.y);
}
__global__ void k_out_fb(const float* __restrict__ agg2, const float* __restrict__ dis,
                         const float* __restrict__ b2, float* __restrict__ out, int N) {
    int v = blockIdx.x * blockDim.x + threadIdx.x;
    if (v >= N) return;
    float d = dis[v];
    out[v * 2 + 0] = agg2[v * 2 + 0] * d + b2[0];
    out[v * 2 + 1] = agg2[v * 2 + 1] * d + b2[1];
}

// ---------------- launch ----------------

extern "C" void kernel_launch(void* const* d_in, const int* in_sizes, int n_in,
                              void* d_out, int out_size, void* d_ws, size_t ws_size,
                              hipStream_t stream) {
    const float* x  = (const float*)d_in[0];
    const int*   ei = (const int*)d_in[1];
    const float* W1 = (const float*)d_in[2];
    const float* b1 = (const float*)d_in[3];
    const float* W2 = (const float*)d_in[4];
    const float* b2 = (const float*)d_in[5];

    const int N = in_sizes[0] / 4;
    const int E = in_sizes[1] / 2;
    const int* src = ei;
    const int* dst = ei + E;
    float* outp = (float*)d_out;

    auto align = [](size_t v) { return (v + 255) & ~(size_t)255; };
    const int NBC = (N + CN - 1) >> CSH;              // 98
    const int gN  = (N + TPB - 1) / TPB;
    const int ntiles = (E + STILE - 1) / STILE;       // 1563
    const bool src_fits = (size_t)N <= ((size_t)1 << (32 - CSH));
    const bool fx_safe = (long long)E <= (long long)N * 512;

    const int S1 = 16, S2 = 16;
    size_t part1_bytes = (size_t)NBC * S1 * CN * 16;
    size_t part2_bytes = (size_t)NBC * S2 * CN * 8;
    size_t part_max = part1_bytes > part2_bytes ? part1_bytes : part2_bytes;

    size_t need_new = align((size_t)E * 4)               /* packed */
                    + align(part_max)                    /* partial1 / partial2 aliased */
                    + align((size_t)N * 16)              /* xs */
                    + align((size_t)N * 16)              /* xse */
                    + align((size_t)N * 8)               /* hs2f */
                    + align((size_t)N * 8)               /* hs2e */
                    + align((size_t)N * 4)               /* deg */
                    + align((size_t)NBC * 4)             /* bsize */
                    + align((size_t)NBC * 4)             /* cur */
                    + align((size_t)(NBC + 1) * 4);      /* base */

    if (ws_size >= need_new && NBC <= NBC_MAX && src_fits && fx_safe) {
        char* ws = (char*)d_ws;
        unsigned* packed = (unsigned*)ws; ws += align((size_t)E * 4);
        u64* partial1 = (u64*)ws;           // aliased: live agg1u..comb1q
        u64* partial2 = (u64*)ws;           // aliased: live agg2u..comb2q
        ws += align(part_max);
        float* xs    = (float*)ws;    ws += align((size_t)N * 16);
        unsigned* xse = (unsigned*)ws; ws += align((size_t)N * 16);
        float* hs2f  = (float*)ws;    ws += align((size_t)N * 8);
        unsigned* hs2e = (unsigned*)ws; ws += align((size_t)N * 8);
        int* deg     = (int*)ws;      ws += align((size_t)N * 4);
        int* bsize   = (int*)ws;      ws += align((size_t)NBC * 4);
        int* cur     = (int*)ws;      ws += align((size_t)NBC * 4);
        int* base    = (int*)ws;      ws += align((size_t)(NBC + 1) * 4);

        k_zero<<<gN, TPB, 0, stream>>>(deg, N);
        if ((E & 3) == 0) {
            int E4 = E >> 2;
            k_degg_v<<<(E4 + TPB - 1) / TPB, TPB, 0, stream>>>(dst, deg, E4);
        } else {
            k_degg_s<<<2048, TPB, 0, stream>>>(dst, deg, E);
        }
        k_bsum<<<NBC, TPB, 0, stream>>>(deg, bsize, N);
        k_scanbase<<<1, TPB, 0, stream>>>(bsize, base, cur, NBC);
        k_prepv<<<gN, TPB, 0, stream>>>(x, deg, xs, xse, N);
        k_bscat<<<ntiles, TPB, 0, stream>>>(src, dst, cur, packed, E, NBC);
        k_agg1u<<<NBC * S1, TPB, 0, stream>>>(packed, base, xse, partial1, S1);
        k_comb1q<<<gN, TPB, 0, stream>>>(partial1, xs, deg, W1, b1, W2, hs2f, hs2e, S1, N);
        k_agg2u<<<NBC * S2, TPB, 0, stream>>>(packed, base, hs2e, partial2, S2);
        k_comb2q<<<gN, TPB, 0, stream>>>(partial2, hs2f, deg, b2, outp, S2, N);
    } else {
        // fallback: R1 atomic-scatter pipeline
        char* ws = (char*)d_ws;
        int*   deg  = (int*)ws;   ws += align((size_t)N * 4);
        float* dis  = (float*)ws; ws += align((size_t)N * 4);
        float* hs1  = (float*)ws; ws += align((size_t)N * 16 * 4);
        float* agg1 = (float*)ws; ws += align((size_t)N * 16 * 4);
        float* hs2  = (float*)ws; ws += align((size_t)N * 2 * 4);
        float* agg2 = (float*)ws; ws += align((size_t)N * 2 * 4);
        int gE = (E + TPB - 1) / TPB;
        int gE4 = ((size_t)E * 4 + TPB - 1) / TPB;

        k_zero<<<gN, TPB, 0, stream>>>(deg, N);
        k_deg_fb<<<gE, TPB, 0, stream>>>(dst, deg, E);
        k_dis_fb<<<gN, TPB, 0, stream>>>(deg, dis, N);
        k_lin1_fb<<<gN, TPB, 0, stream>>>(x, W1, dis, hs1, agg1, N);
        k_scat1_fb<<<gE4, TPB, 0, stream>>>(src, dst, hs1, agg1, E * 4);
        k_lin2_fb<<<gN, TPB, 0, stream>>>(agg1, dis, b1, W2, hs2, agg2, N);
        k_scat2_fb<<<gE, TPB, 0, stream>>>(src, dst, hs2, agg2, E);
        k_out_fb<<<gN, TPB, 0, stream>>>(agg2, dis, b2, outp, N);
    }
}

// Round 6
// 271.071 us; speedup vs baseline: 1.7642x; 1.7642x over previous
//
#include <hip/hip_runtime.h>

#define TPB 256
#define CSH 10                 // nodes per dst bucket = 1024
#define CN 1024
#define NBC_MAX 128
#define STILE 8192
#define EPT (STILE / TPB)

#define P2 16                  // stage-2 blocks per bucket (16KB write windows)
#define P2_SH 4
#define SB_SH 8                // src-block granularity = 256 nodes
#define SBN_MAX 512            // max src-blocks (N <= 131072)

// fixed-point packing: value -> (int)rn(v*SCALE) + BIAS, two per u64
#define B20 1048576            // bias 2^20
#define S1F 131072.0f          // layer-1 scale 2^17
#define S2F 8192.0f            // layer-2 scale 2^13

typedef unsigned long long u64;

__device__ __forceinline__ unsigned enc_fx(float v, float scale) {
    int xi = __float2int_rn(v * scale);
    xi = max(-(B20 - 1), min(B20 - 1, xi));
    return (unsigned)(xi + B20);
}

__global__ void k_zero2(int* __restrict__ a, int na, int* __restrict__ b, int nb) {
    int i = blockIdx.x * blockDim.x + threadIdx.x;
    if (i < na) a[i] = 0;
    if (i < nb) b[i] = 0;
}

// per-bucket edge counts (98 bins): LDS histogram per block, one flush atomic per bin
__global__ void k_hist0(const int* __restrict__ dst, int* __restrict__ hist0,
                        int NBC, int E) {
    __shared__ int hh[NBC_MAX];
    for (int i = threadIdx.x; i < NBC_MAX; i += TPB) hh[i] = 0;
    __syncthreads();
    int stride = gridDim.x * blockDim.x;
    for (int i = blockIdx.x * blockDim.x + threadIdx.x; i < E; i += stride)
        atomicAdd(&hh[dst[i] >> CSH], 1);
    __syncthreads();
    for (int i = threadIdx.x; i < NBC; i += TPB)
        if (hh[i]) atomicAdd(&hist0[i], hh[i]);
}

// exclusive scan of bucket sizes -> base[0..NBC]; also init bulk-reserve cursors
__global__ void k_scanbase(const int* __restrict__ bsize, int* __restrict__ base,
                           int* __restrict__ cur, int NBC) {
    __shared__ int s[NBC_MAX];
    int t = threadIdx.x;
    if (t < NBC_MAX) s[t] = (t < NBC) ? bsize[t] : 0;
    __syncthreads();
    for (int off = 1; off < NBC_MAX; off <<= 1) {
        int v = 0;
        if (t < NBC_MAX && t >= off) v = s[t - off];
        __syncthreads();
        if (t < NBC_MAX) s[t] += v;
        __syncthreads();
    }
    if (t < NBC) {
        int b = (t == 0) ? 0 : s[t - 1];
        base[t] = b;
        cur[t] = b;
    }
    if (t == 0) base[NBC] = s[NBC - 1];
}

// stage 1: bucket scatter (R4-measured 49us). In-LDS grouping by dst-bucket,
// per-bin BULK cursor reservation, wave-coalesced burst flush.
__global__ void k_bscat(const int* __restrict__ src, const int* __restrict__ dst,
                        int* __restrict__ cur, unsigned* __restrict__ packed,
                        int E, int NBC) {
    __shared__ unsigned stage[STILE];          // 32 KB
    __shared__ int cnt[NBC_MAX], lb[NBC_MAX], resv[NBC_MAX];
    int tb = blockIdx.x * STILE;
    int te = min(E, tb + STILE);
    if (threadIdx.x < NBC_MAX) cnt[threadIdx.x] = 0;
    __syncthreads();
    unsigned pk[EPT];
    int br[EPT];   // bucket | rank<<7  (bucket < 128)
#pragma unroll
    for (int u = 0; u < EPT; u++) {
        int i = tb + u * TPB + (int)threadIdx.x;
        br[u] = -1;
        if (i < te) {
            int d = dst[i];
            int b = d >> CSH;
            pk[u] = ((unsigned)src[i] << CSH) | (unsigned)(d & (CN - 1));
            int r = atomicAdd(&cnt[b], 1);     // rank doubles as count
            br[u] = b | (r << 7);
        }
    }
    __syncthreads();
    if (threadIdx.x < (unsigned)NBC) {
        int b = threadIdx.x;
        int sum = 0;
        for (int j = 0; j < b; j++) sum += cnt[j];   // same-addr broadcast reads
        lb[b] = sum;
        resv[b] = cnt[b] ? atomicAdd(&cur[b], cnt[b]) : 0;
    }
    __syncthreads();
#pragma unroll
    for (int u = 0; u < EPT; u++) {
        if (br[u] >= 0) {
            int b = br[u] & (NBC_MAX - 1);
            stage[lb[b] + (br[u] >> 7)] = pk[u];
        }
    }
    __syncthreads();
    int wv = threadIdx.x >> 6, lane = threadIdx.x & 63;
    for (int b = wv; b < NBC; b += 4) {        // burst flush, coalesced
        int c = cnt[b];
        if (!c) continue;
        int gb = resv[b], s0 = lb[b];
        for (int i = lane; i < c; i += 64)
            packed[gb + i] = stage[s0 + i];
    }
}

// stage 2a: per (bucket, p) block reads its CONTIGUOUS slice (uint4-vectorized),
// histograms src-blocks (for the cell sort) and dst-nodes (degrees).
__global__ void k_p2hist(const unsigned* __restrict__ packed, const int* __restrict__ base,
                         int* __restrict__ h, int* __restrict__ deg, int SBN, int N) {
    __shared__ int hsb[SBN_MAX];
    __shared__ int dcnt[CN];
    int b = blockIdx.x >> P2_SH, p = blockIdx.x & (P2 - 1);
    for (int i = threadIdx.x; i < SBN_MAX; i += TPB) hsb[i] = 0;
    for (int i = threadIdx.x; i < CN; i += TPB) dcnt[i] = 0;
    __syncthreads();
    int lo = base[b], sz = base[b + 1] - lo;
    int i0 = lo + (int)((long long)sz * p / P2);
    int i1 = lo + (int)((long long)sz * (p + 1) / P2);
    int a0 = min(i1, (i0 + 3) & ~3);
    int a1 = a0 + ((i1 - a0) & ~3);
    for (int i = i0 + (int)threadIdx.x; i < a0; i += TPB) {   // head
        unsigned pk = packed[i];
        atomicAdd(&hsb[pk >> (CSH + SB_SH)], 1);
        atomicAdd(&dcnt[pk & (CN - 1)], 1);
    }
    for (int i = a0 + (int)threadIdx.x * 4; i < a1; i += TPB * 4) {  // body
        uint4 q = *(const uint4*)(packed + i);
        atomicAdd(&hsb[q.x >> (CSH + SB_SH)], 1); atomicAdd(&dcnt[q.x & (CN - 1)], 1);
        atomicAdd(&hsb[q.y >> (CSH + SB_SH)], 1); atomicAdd(&dcnt[q.y & (CN - 1)], 1);
        atomicAdd(&hsb[q.z >> (CSH + SB_SH)], 1); atomicAdd(&dcnt[q.z & (CN - 1)], 1);
        atomicAdd(&hsb[q.w >> (CSH + SB_SH)], 1); atomicAdd(&dcnt[q.w & (CN - 1)], 1);
    }
    for (int i = a1 + (int)threadIdx.x; i < i1; i += TPB) {   // tail
        unsigned pk = packed[i];
        atomicAdd(&hsb[pk >> (CSH + SB_SH)], 1);
        atomicAdd(&dcnt[pk & (CN - 1)], 1);
    }
    __syncthreads();
    int* hp = h + (size_t)blockIdx.x * SBN;
    for (int i2 = threadIdx.x; i2 < SBN; i2 += TPB) hp[i2] = hsb[i2];
    int node0 = b << CSH;
    for (int i2 = threadIdx.x; i2 < CN; i2 += TPB)
        if (dcnt[i2] && node0 + i2 < N) atomicAdd(&deg[node0 + i2], dcnt[i2]);
}

// in-place h -> exclusive cell bases, per bucket, (sb-major, p-minor) order
// => packed2 layout [bucket][src-block][p]: full-cell gather contiguity.
__global__ void k_scan3(int* __restrict__ h, const int* __restrict__ base, int SBN) {
    __shared__ int tsum[TPB];
    int b = blockIdx.x;
    int* hb = h + (size_t)b * P2 * SBN;
    int n = SBN * P2;                    // logical idx = sb*P2 + p
    int per = (n + TPB - 1) / TPB;       // <= 32
    int i0 = threadIdx.x * per;
    int vals[32];
    int sum = 0;
    for (int k = 0; k < per && k < 32; k++) {
        int idx = i0 + k;
        int v = 0;
        if (idx < n) {
            int sb = idx >> P2_SH, p = idx & (P2 - 1);
            v = hb[p * SBN + sb];
        }
        vals[k] = v;
        sum += v;
    }
    tsum[threadIdx.x] = sum;
    __syncthreads();
    for (int off = 1; off < TPB; off <<= 1) {
        int v = (threadIdx.x >= off) ? tsum[threadIdx.x - off] : 0;
        __syncthreads();
        tsum[threadIdx.x] += v;
        __syncthreads();
    }
    int run = base[b] + ((threadIdx.x == 0) ? 0 : tsum[threadIdx.x - 1]);
    for (int k = 0; k < per && k < 32; k++) {
        int idx = i0 + k;
        if (idx < n) {
            int sb = idx >> P2_SH, p = idx & (P2 - 1);
            hb[p * SBN + sb] = run;
            run += vals[k];
        }
    }
}

// stage 2b: re-read the same contiguous slice (uint4), scatter to packed2 via
// LDS rank cursors. 16KB per-block write windows: concurrent live windows per
// XCD ~1.8MB << 4MB L2 => lines fill & merge before eviction (R4's 4.3x write
// amp came from 3.6MB of concurrent 32KB windows thrashing the XCD L2).
__global__ void k_p2scat(const unsigned* __restrict__ packed, const int* __restrict__ base,
                         const int* __restrict__ h, unsigned* __restrict__ packed2,
                         int SBN) {
    __shared__ int goff[SBN_MAX];
    __shared__ int cnt2[SBN_MAX];
    int b = blockIdx.x >> P2_SH, p = blockIdx.x & (P2 - 1);
    const int* hp = h + (size_t)blockIdx.x * SBN;
    for (int i = threadIdx.x; i < SBN_MAX; i += TPB) {
        cnt2[i] = 0;
        goff[i] = (i < SBN) ? hp[i] : 0;
    }
    __syncthreads();
    int lo = base[b], sz = base[b + 1] - lo;
    int i0 = lo + (int)((long long)sz * p / P2);
    int i1 = lo + (int)((long long)sz * (p + 1) / P2);
    int a0 = min(i1, (i0 + 3) & ~3);
    int a1 = a0 + ((i1 - a0) & ~3);
    for (int i = i0 + (int)threadIdx.x; i < a0; i += TPB) {   // head
        unsigned pk = packed[i];
        int sb2 = pk >> (CSH + SB_SH);
        int r = atomicAdd(&cnt2[sb2], 1);
        packed2[goff[sb2] + r] = pk;
    }
    for (int i = a0 + (int)threadIdx.x * 4; i < a1; i += TPB * 4) {  // body
        uint4 q = *(const uint4*)(packed + i);
        int sa = q.x >> (CSH + SB_SH), sb_ = q.y >> (CSH + SB_SH);
        int sc = q.z >> (CSH + SB_SH), sd = q.w >> (CSH + SB_SH);
        int ra = atomicAdd(&cnt2[sa], 1);      // 4 independent rank chains
        int rb = atomicAdd(&cnt2[sb_], 1);
        int rc = atomicAdd(&cnt2[sc], 1);
        int rd = atomicAdd(&cnt2[sd], 1);
        packed2[goff[sa] + ra] = q.x;
        packed2[goff[sb_] + rb] = q.y;
        packed2[goff[sc] + rc] = q.z;
        packed2[goff[sd] + rd] = q.w;
    }
    for (int i = a1 + (int)threadIdx.x; i < i1; i += TPB) {   // tail
        unsigned pk = packed[i];
        int sb2 = pk >> (CSH + SB_SH);
        int r = atomicAdd(&cnt2[sb2], 1);
        packed2[goff[sb2] + r] = pk;
    }
}

// xs = x * rsqrt(deg+1) (float4 self-term) and encoded uint4 for gathers
__global__ void k_prepv(const float* __restrict__ x, const int* __restrict__ deg,
                        float* __restrict__ xs, unsigned* __restrict__ xse, int N) {
    int v = blockIdx.x * blockDim.x + threadIdx.x;
    if (v >= N) return;
    float di = rsqrtf((float)(deg[v] + 1));
    float4 xv = ((const float4*)x)[v];
    xv.x *= di; xv.y *= di; xv.z *= di; xv.w *= di;
    ((float4*)xs)[v] = xv;
    uint4 e;
    e.x = enc_fx(xv.x, S1F); e.y = enc_fx(xv.y, S1F);
    e.z = enc_fx(xv.z, S1F); e.w = enc_fx(xv.w, S1F);
    ((uint4*)xse)[v] = e;
}

#define AGG1_AT(pkv, gv) { int n_ = (int)((pkv) & (CN - 1)) * 3; \
    atomicAdd(&acc[n_],     (u64)(gv).x | ((u64)(gv).y << 32)); \
    atomicAdd(&acc[n_ + 1], (u64)(gv).z | ((u64)(gv).w << 32)); }

// layer-1 edge pass: contiguous stream over src-sorted packed2 (R2/R4-proven)
__global__ void k_agg1n(const unsigned* __restrict__ packed2, const int* __restrict__ base,
                        const unsigned* __restrict__ xse, u64* __restrict__ partial1, int S1) {
    __shared__ u64 acc[CN * 3];   // stride 3 u64 to spread banks; 24 KB
    for (int i = threadIdx.x; i < CN * 3; i += TPB) acc[i] = 0ULL;
    __syncthreads();
    int b = blockIdx.x / S1, s = blockIdx.x - b * S1;
    int lo = base[b], sz = base[b + 1] - lo;
    int i0 = lo + (int)((long long)sz * s / S1);
    int i1 = lo + (int)((long long)sz * (s + 1) / S1);
    const uint4* xse4 = (const uint4*)xse;
    int i = i0 + (int)threadIdx.x;
    for (; i + 3 * TPB < i1; i += 4 * TPB) {
        unsigned pa = packed2[i];
        unsigned pb = packed2[i + TPB];
        unsigned pc = packed2[i + 2 * TPB];
        unsigned pd = packed2[i + 3 * TPB];
        uint4 ga = xse4[pa >> CSH];
        uint4 gb = xse4[pb >> CSH];
        uint4 gc = xse4[pc >> CSH];
        uint4 gd = xse4[pd >> CSH];
        AGG1_AT(pa, ga); AGG1_AT(pb, gb); AGG1_AT(pc, gc); AGG1_AT(pd, gd);
    }
    for (; i < i1; i += TPB) {
        unsigned pk = packed2[i];
        uint4 g = xse4[pk >> CSH];
        AGG1_AT(pk, g);
    }
    __syncthreads();
    u64* p = partial1 + (size_t)blockIdx.x * (CN * 2);
    for (int i2 = threadIdx.x; i2 < CN * 2; i2 += TPB)
        p[i2] = acc[(i2 >> 1) * 3 + (i2 & 1)];
}

// layer-1 combine: decode fixed-point, +self, *dis -> MLP -> hs2 (float + encoded)
__global__ void k_comb1q(const u64* __restrict__ partial1,
                         const float* __restrict__ xs, const int* __restrict__ deg,
                         const float* __restrict__ W1, const float* __restrict__ b1,
                         const float* __restrict__ W2,
                         float* __restrict__ hs2f, unsigned* __restrict__ hs2e,
                         int S1, int N) {
    __shared__ float w1[64], w2[32], bb[16];
    if (threadIdx.x < 64) w1[threadIdx.x] = W1[threadIdx.x];
    if (threadIdx.x < 32) w2[threadIdx.x] = W2[threadIdx.x];
    if (threadIdx.x < 16) bb[threadIdx.x] = b1[threadIdx.x];
    __syncthreads();
    int v = blockIdx.x * blockDim.x + threadIdx.x;
    if (v >= N) return;
    int b = v >> CSH, lv = v & (CN - 1);
    u64 a01 = 0, a23 = 0;
    for (int s = 0; s < S1; s++) {
        const u64* q = partial1 + ((size_t)(b * S1 + s) * CN + lv) * 2;
        a01 += q[0];
        a23 += q[1];
    }
    int dg = deg[v];
    long long bias = (long long)dg << 20;
    const float inv = 1.0f / S1F;
    float f0 = (float)((long long)(a01 & 0xffffffffULL) - bias) * inv;
    float f1 = (float)((long long)(a01 >> 32) - bias) * inv;
    float f2 = (float)((long long)(a23 & 0xffffffffULL) - bias) * inv;
    float f3 = (float)((long long)(a23 >> 32) - bias) * inv;
    float4 self = ((const float4*)xs)[v];
    float di = rsqrtf((float)(dg + 1));
    float v0 = (f0 + self.x) * di, v1 = (f1 + self.y) * di;
    float v2 = (f2 + self.z) * di, v3 = (f3 + self.w) * di;
    float s0 = 0.f, s1 = 0.f;
#pragma unroll
    for (int j = 0; j < 16; j++) {
        float h = v0 * w1[j] + v1 * w1[16 + j] + v2 * w1[32 + j] + v3 * w1[48 + j] + bb[j];
        h = fmaxf(h, 0.0f);
        s0 += h * w2[2 * j];
        s1 += h * w2[2 * j + 1];
    }
    s0 *= di; s1 *= di;
    ((float2*)hs2f)[v] = make_float2(s0, s1);
    uint2 e;
    e.x = enc_fx(s0, S2F);
    e.y = enc_fx(s1, S2F);
    ((uint2*)hs2e)[v] = e;
}

// layer-2 edge pass: contiguous stream over src-sorted packed2 (R2/R4-proven)
__global__ void k_agg2n(const unsigned* __restrict__ packed2, const int* __restrict__ base,
                        const unsigned* __restrict__ hs2e, u64* __restrict__ partial2, int S2) {
    __shared__ u64 acc[CN];   // 8 KB
    for (int i = threadIdx.x; i < CN; i += TPB) acc[i] = 0ULL;
    __syncthreads();
    int b = blockIdx.x / S2, s = blockIdx.x - b * S2;
    int lo = base[b], sz = base[b + 1] - lo;
    int i0 = lo + (int)((long long)sz * s / S2);
    int i1 = lo + (int)((long long)sz * (s + 1) / S2);
    const uint2* h2 = (const uint2*)hs2e;
    int i = i0 + (int)threadIdx.x;
    for (; i + 3 * TPB < i1; i += 4 * TPB) {
        unsigned pa = packed2[i];
        unsigned pb = packed2[i + TPB];
        unsigned pc = packed2[i + 2 * TPB];
        unsigned pd = packed2[i + 3 * TPB];
        uint2 ga = h2[pa >> CSH];
        uint2 gb = h2[pb >> CSH];
        uint2 gc = h2[pc >> CSH];
        uint2 gd = h2[pd >> CSH];
        atomicAdd(&acc[pa & (CN - 1)], (u64)ga.x | ((u64)ga.y << 32));
        atomicAdd(&acc[pb & (CN - 1)], (u64)gb.x | ((u64)gb.y << 32));
        atomicAdd(&acc[pc & (CN - 1)], (u64)gc.x | ((u64)gc.y << 32));
        atomicAdd(&acc[pd & (CN - 1)], (u64)gd.x | ((u64)gd.y << 32));
    }
    for (; i < i1; i += TPB) {
        unsigned pk = packed2[i];
        uint2 g = h2[pk >> CSH];
        atomicAdd(&acc[pk & (CN - 1)], (u64)g.x | ((u64)g.y << 32));
    }
    __syncthreads();
    u64* p = partial2 + (size_t)blockIdx.x * CN;
    for (int i2 = threadIdx.x; i2 < CN; i2 += TPB) p[i2] = acc[i2];
}

// layer-2 combine: decode, +self, *dis, +bias -> out
__global__ void k_comb2q(const u64* __restrict__ partial2,
                         const float* __restrict__ hs2f, const int* __restrict__ deg,
                         const float* __restrict__ b2, float* __restrict__ out,
                         int S2, int N) {
    int v = blockIdx.x * blockDim.x + threadIdx.x;
    if (v >= N) return;
    int b = v >> CSH, lv = v & (CN - 1);
    u64 t = 0;
    for (int s = 0; s < S2; s++)
        t += partial2[(size_t)(b * S2 + s) * CN + lv];
    int dg = deg[v];
    long long bias = (long long)dg << 20;
    const float inv = 1.0f / S2F;
    float f0 = (float)((long long)(t & 0xffffffffULL) - bias) * inv;
    float f1 = (float)((long long)(t >> 32) - bias) * inv;
    float2 self = ((const float2*)hs2f)[v];
    float di = rsqrtf((float)(dg + 1));
    ((float2*)out)[v] = make_float2((f0 + self.x) * di + b2[0],
                                    (f1 + self.y) * di + b2[1]);
}

// ---------------- fallback (R1 atomic pipeline) ----------------

__global__ void k_zero(int* __restrict__ p, int n) {
    int i = blockIdx.x * blockDim.x + threadIdx.x;
    if (i < n) p[i] = 0;
}
__global__ void k_deg_fb(const int* __restrict__ dst, int* __restrict__ deg, int E) {
    int i = blockIdx.x * blockDim.x + threadIdx.x;
    if (i < E) atomicAdd(&deg[dst[i]], 1);
}
__global__ void k_dis_fb(const int* __restrict__ deg, float* __restrict__ dis, int N) {
    int v = blockIdx.x * blockDim.x + threadIdx.x;
    if (v < N) dis[v] = rsqrtf((float)(deg[v] + 1));
}
__global__ void k_lin1_fb(const float* __restrict__ x, const float* __restrict__ W1,
                          const float* __restrict__ dis, float* __restrict__ hs1,
                          float* __restrict__ agg1, int N) {
    __shared__ float w[64];
    if (threadIdx.x < 64) w[threadIdx.x] = W1[threadIdx.x];
    __syncthreads();
    int v = blockIdx.x * blockDim.x + threadIdx.x;
    if (v >= N) return;
    float4 xv = ((const float4*)x)[v];
    float d = dis[v];
#pragma unroll
    for (int j = 0; j < 16; j++) {
        float h = (xv.x * w[j] + xv.y * w[16 + j] + xv.z * w[32 + j] + xv.w * w[48 + j]) * d;
        hs1[v * 16 + j] = h;
        agg1[v * 16 + j] = h;
    }
}
__global__ void k_scat1_fb(const int* __restrict__ src, const int* __restrict__ dst,
                           const float* __restrict__ hs1, float* __restrict__ agg1, int E4) {
    int t = blockIdx.x * blockDim.x + threadIdx.x;
    if (t >= E4) return;
    int e = t >> 2, q = t & 3;
    int s = src[e], d = dst[e];
    float4 m = ((const float4*)hs1)[s * 4 + q];
    float* a = agg1 + (size_t)d * 16 + q * 4;
    atomicAdd(a + 0, m.x); atomicAdd(a + 1, m.y);
    atomicAdd(a + 2, m.z); atomicAdd(a + 3, m.w);
}
__global__ void k_lin2_fb(const float* __restrict__ agg1, const float* __restrict__ dis,
                          const float* __restrict__ b1, const float* __restrict__ W2,
                          float* __restrict__ hs2, float* __restrict__ agg2, int N) {
    __shared__ float w[32];
    __shared__ float bb[16];
    if (threadIdx.x < 32) w[threadIdx.x] = W2[threadIdx.x];
    if (threadIdx.x < 16) bb[threadIdx.x] = b1[threadIdx.x];
    __syncthreads();
    int v = blockIdx.x * blockDim.x + threadIdx.x;
    if (v >= N) return;
    float d = dis[v];
    float a0 = 0.f, a1 = 0.f;
#pragma unroll
    for (int k = 0; k < 16; k++) {
        float r = fmaxf(agg1[v * 16 + k] * d + bb[k], 0.0f);
        a0 += r * w[k * 2 + 0];
        a1 += r * w[k * 2 + 1];
    }
    float2 hv = make_float2(a0 * d, a1 * d);
    ((float2*)hs2)[v] = hv;
    ((float2*)agg2)[v] = hv;
}
__global__ void k_scat2_fb(const int* __restrict__ src, const int* __restrict__ dst,
                           const float* __restrict__ hs2, float* __restrict__ agg2, int E) {
    int e = blockIdx.x * blockDim.x + threadIdx.x;
    if (e >= E) return;
    int s = src[e], d = dst[e];
    float2 m = ((const float2*)hs2)[s];
    atomicAdd(&agg2[d * 2 + 0], m.x);
    atomicAdd(&agg2[d * 2 + 1], m.y);
}
__global__ void k_out_fb(const float* __restrict__ agg2, const float* __restrict__ dis,
                         const float* __restrict__ b2, float* __restrict__ out, int N) {
    int v = blockIdx.x * blockDim.x + threadIdx.x;
    if (v >= N) return;
    float d = dis[v];
    out[v * 2 + 0] = agg2[v * 2 + 0] * d + b2[0];
    out[v * 2 + 1] = agg2[v * 2 + 1] * d + b2[1];
}

// ---------------- launch ----------------

extern "C" void kernel_launch(void* const* d_in, const int* in_sizes, int n_in,
                              void* d_out, int out_size, void* d_ws, size_t ws_size,
                              hipStream_t stream) {
    const float* x  = (const float*)d_in[0];
    const int*   ei = (const int*)d_in[1];
    const float* W1 = (const float*)d_in[2];
    const float* b1 = (const float*)d_in[3];
    const float* W2 = (const float*)d_in[4];
    const float* b2 = (const float*)d_in[5];

    const int N = in_sizes[0] / 4;
    const int E = in_sizes[1] / 2;
    const int* src = ei;
    const int* dst = ei + E;
    float* outp = (float*)d_out;

    auto align = [](size_t v) { return (v + 255) & ~(size_t)255; };
    const int NBC = (N + CN - 1) >> CSH;              // 98
    const int SBN = (N + (1 << SB_SH) - 1) >> SB_SH;  // 391
    const int NC  = NBC * P2 * SBN;                   // h entries
    const int gN  = (N + TPB - 1) / TPB;
    const int ntiles = (E + STILE - 1) / STILE;       // 782
    const bool src_fits = (size_t)N <= ((size_t)1 << (32 - CSH));
    const bool fx_safe = (long long)E <= (long long)N * 512;

    const int S1 = 16, S2 = 16;
    size_t part1_bytes = (size_t)NBC * S1 * CN * 16;
    size_t part2_bytes = (size_t)NBC * S2 * CN * 8;
    size_t pkA_bytes = (size_t)E * 4;                 // packed, later partial1/2
    if (part1_bytes > pkA_bytes) pkA_bytes = part1_bytes;
    if (part2_bytes > pkA_bytes) pkA_bytes = part2_bytes;

    size_t need_new = align(pkA_bytes)                   /* packed / partial1 / partial2 */
                    + align((size_t)E * 4)               /* packed2 */
                    + align((size_t)N * 16)              /* xs */
                    + align((size_t)N * 16)              /* xse */
                    + align((size_t)N * 8)               /* hs2f */
                    + align((size_t)N * 8)               /* hs2e */
                    + align((size_t)N * 4)               /* deg */
                    + align((size_t)NC * 4)              /* h */
                    + align((size_t)NBC * 4)             /* hist0 */
                    + align((size_t)NBC * 4)             /* cur */
                    + align((size_t)(NBC + 1) * 4);      /* base */

    if (ws_size >= need_new && NBC <= NBC_MAX && SBN <= SBN_MAX && src_fits && fx_safe) {
        char* ws = (char*)d_ws;
        unsigned* packed = (unsigned*)ws;   // dead after p2scat
        u64* partial1 = (u64*)ws;           // aliased: live agg1n..comb1q
        u64* partial2 = (u64*)ws;           // aliased: live agg2n..comb2q
        ws += align(pkA_bytes);
        unsigned* packed2 = (unsigned*)ws; ws += align((size_t)E * 4);
        float* xs    = (float*)ws;    ws += align((size_t)N * 16);
        unsigned* xse = (unsigned*)ws; ws += align((size_t)N * 16);
        float* hs2f  = (float*)ws;    ws += align((size_t)N * 8);
        unsigned* hs2e = (unsigned*)ws; ws += align((size_t)N * 8);
        int* deg     = (int*)ws;      ws += align((size_t)N * 4);
        int* h       = (int*)ws;      ws += align((size_t)NC * 4);
        int* hist0   = (int*)ws;      ws += align((size_t)NBC * 4);
        int* cur     = (int*)ws;      ws += align((size_t)NBC * 4);
        int* base    = (int*)ws;      ws += align((size_t)(NBC + 1) * 4);

        k_zero2<<<gN, TPB, 0, stream>>>(deg, N, hist0, NBC);
        k_hist0<<<1024, TPB, 0, stream>>>(dst, hist0, NBC, E);
        k_scanbase<<<1, TPB, 0, stream>>>(hist0, base, cur, NBC);
        k_bscat<<<ntiles, TPB, 0, stream>>>(src, dst, cur, packed, E, NBC);
        k_p2hist<<<NBC * P2, TPB, 0, stream>>>(packed, base, h, deg, SBN, N);
        k_scan3<<<NBC, TPB, 0, stream>>>(h, base, SBN);
        k_p2scat<<<NBC * P2, TPB, 0, stream>>>(packed, base, h, packed2, SBN);
        k_prepv<<<gN, TPB, 0, stream>>>(x, deg, xs, xse, N);
        k_agg1n<<<NBC * S1, TPB, 0, stream>>>(packed2, base, xse, partial1, S1);
        k_comb1q<<<gN, TPB, 0, stream>>>(partial1, xs, deg, W1, b1, W2, hs2f, hs2e, S1, N);
        k_agg2n<<<NBC * S2, TPB, 0, stream>>>(packed2, base, hs2e, partial2, S2);
        k_comb2q<<<gN, TPB, 0, stream>>>(partial2, hs2f, deg, b2, outp, S2, N);
    } else {
        // fallback: R1 atomic-scatter pipeline
        char* ws = (char*)d_ws;
        int*   deg  = (int*)ws;   ws += align((size_t)N * 4);
        float* dis  = (float*)ws; ws += align((size_t)N * 4);
        float* hs1  = (float*)ws; ws += align((size_t)N * 16 * 4);
        float* agg1 = (float*)ws; ws += align((size_t)N * 16 * 4);
        float* hs2  = (float*)ws; ws += align((size_t)N * 2 * 4);
        float* agg2 = (float*)ws; ws += align((size_t)N * 2 * 4);
        int gE = (E + TPB - 1) / TPB;
        int gE4 = ((size_t)E * 4 + TPB - 1) / TPB;

        k_zero<<<gN, TPB, 0, stream>>>(deg, N);
        k_deg_fb<<<gE, TPB, 0, stream>>>(dst, deg, E);
        k_dis_fb<<<gN, TPB, 0, stream>>>(deg, dis, N);
        k_lin1_fb<<<gN, TPB, 0, stream>>>(x, W1, dis, hs1, agg1, N);
        k_scat1_fb<<<gE4, TPB, 0, stream>>>(src, dst, hs1, agg1, E * 4);
        k_lin2_fb<<<gN, TPB, 0, stream>>>(agg1, dis, b1, W2, hs2, agg2, N);
        k_scat2_fb<<<gE, TPB, 0, stream>>>(src, dst, hs2, agg2, E);
        k_out_fb<<<gN, TPB, 0, stream>>>(agg2, dis, b2, outp, N);
    }
}

// Round 7
// 258.449 us; speedup vs baseline: 1.8504x; 1.0488x over previous
//
#include <hip/hip_runtime.h>

#define TPB 256
#define CSH 10                 // nodes per dst bucket = 1024
#define CN 1024
#define NBC_MAX 128
#define STILE 4096             // bscat tile (16 KB stage -> 8 blocks/CU)
#define EPT (STILE / TPB)      // 16

#define P2 16                  // stage-2 blocks per bucket
#define P2_SH 4
#define SB_SH 8                // src-block granularity = 256 nodes
#define SBN_MAX 512            // max src-blocks (N <= 131072)
#define CAP 20                 // p2scat staged entries per bin (mean ~10.7)

// fixed-point packing: value -> (int)rn(v*SCALE) + BIAS, two per u64
#define B20 1048576            // bias 2^20
#define S1F 131072.0f          // layer-1 scale 2^17
#define S2F 8192.0f            // layer-2 scale 2^13

typedef unsigned long long u64;

__device__ __forceinline__ unsigned enc_fx(float v, float scale) {
    int xi = __float2int_rn(v * scale);
    xi = max(-(B20 - 1), min(B20 - 1, xi));
    return (unsigned)(xi + B20);
}

__global__ void k_zero2(int* __restrict__ a, int na, int* __restrict__ b, int nb) {
    int i = blockIdx.x * blockDim.x + threadIdx.x;
    if (i < na) a[i] = 0;
    if (i < nb) b[i] = 0;
}

// per-bucket edge counts (98 bins): LDS histogram, int4 reads, one flush atomic/bin
__global__ void k_hist0(const int* __restrict__ dst, int* __restrict__ hist0,
                        int NBC, int E) {
    __shared__ int hh[NBC_MAX];
    for (int i = threadIdx.x; i < NBC_MAX; i += TPB) hh[i] = 0;
    __syncthreads();
    int E4 = E >> 2;
    int stride = gridDim.x * blockDim.x;
    for (int i = blockIdx.x * blockDim.x + threadIdx.x; i < E4; i += stride) {
        int4 d4 = ((const int4*)dst)[i];
        atomicAdd(&hh[d4.x >> CSH], 1);
        atomicAdd(&hh[d4.y >> CSH], 1);
        atomicAdd(&hh[d4.z >> CSH], 1);
        atomicAdd(&hh[d4.w >> CSH], 1);
    }
    if (blockIdx.x == 0) {                     // tail E % 4
        for (int i = (E4 << 2) + (int)threadIdx.x; i < E; i += TPB)
            atomicAdd(&hh[dst[i] >> CSH], 1);
    }
    __syncthreads();
    for (int i = threadIdx.x; i < NBC; i += TPB)
        if (hh[i]) atomicAdd(&hist0[i], hh[i]);
}

// exclusive scan of bucket sizes -> base[0..NBC]; also init bulk-reserve cursors
__global__ void k_scanbase(const int* __restrict__ bsize, int* __restrict__ base,
                           int* __restrict__ cur, int NBC) {
    __shared__ int s[NBC_MAX];
    int t = threadIdx.x;
    if (t < NBC_MAX) s[t] = (t < NBC) ? bsize[t] : 0;
    __syncthreads();
    for (int off = 1; off < NBC_MAX; off <<= 1) {
        int v = 0;
        if (t < NBC_MAX && t >= off) v = s[t - off];
        __syncthreads();
        if (t < NBC_MAX) s[t] += v;
        __syncthreads();
    }
    if (t < NBC) {
        int b = (t == 0) ? 0 : s[t - 1];
        base[t] = b;
        cur[t] = b;
    }
    if (t == 0) base[NBC] = s[NBC - 1];
}

// stage 1: bucket scatter. In-LDS grouping by dst-bucket, per-bin BULK cursor
// reservation, wave-coalesced burst flush (bursts ~42 entries => write amp ~1.1).
// STILE 4096: 18 KB LDS -> 8 blocks/CU (R4's 8192 ran 4/CU at 25% occupancy).
__global__ void k_bscat(const int* __restrict__ src, const int* __restrict__ dst,
                        int* __restrict__ cur, unsigned* __restrict__ packed,
                        int E, int NBC) {
    __shared__ unsigned stage[STILE];          // 16 KB
    __shared__ int cnt[NBC_MAX], lb[NBC_MAX], resv[NBC_MAX];
    int tb = blockIdx.x * STILE;
    int te = min(E, tb + STILE);
    if (threadIdx.x < NBC_MAX) cnt[threadIdx.x] = 0;
    __syncthreads();
    unsigned pk[EPT];
    int br[EPT];   // bucket | rank<<7  (bucket < 128)
#pragma unroll
    for (int u = 0; u < EPT; u++) {
        int i = tb + u * TPB + (int)threadIdx.x;
        br[u] = -1;
        if (i < te) {
            int d = dst[i];
            int b = d >> CSH;
            pk[u] = ((unsigned)src[i] << CSH) | (unsigned)(d & (CN - 1));
            int r = atomicAdd(&cnt[b], 1);     // rank doubles as count
            br[u] = b | (r << 7);
        }
    }
    __syncthreads();
    if (threadIdx.x < (unsigned)NBC) {
        int b = threadIdx.x;
        int sum = 0;
        for (int j = 0; j < b; j++) sum += cnt[j];   // same-addr broadcast reads
        lb[b] = sum;
        resv[b] = cnt[b] ? atomicAdd(&cur[b], cnt[b]) : 0;
    }
    __syncthreads();
#pragma unroll
    for (int u = 0; u < EPT; u++) {
        if (br[u] >= 0) {
            int b = br[u] & (NBC_MAX - 1);
            stage[lb[b] + (br[u] >> 7)] = pk[u];
        }
    }
    __syncthreads();
    int wv = threadIdx.x >> 6, lane = threadIdx.x & 63;
    for (int b = wv; b < NBC; b += 4) {        // burst flush, coalesced
        int c = cnt[b];
        if (!c) continue;
        int gb = resv[b], s0 = lb[b];
        for (int i = lane; i < c; i += 64)
            packed[gb + i] = stage[s0 + i];
    }
}

// stage 2a: per (bucket, p) block reads its CONTIGUOUS slice (uint4-vectorized),
// histograms src-blocks (for the cell sort) and dst-nodes (degrees).
__global__ void k_p2hist(const unsigned* __restrict__ packed, const int* __restrict__ base,
                         int* __restrict__ h, int* __restrict__ deg, int SBN, int N) {
    __shared__ int hsb[SBN_MAX];
    __shared__ int dcnt[CN];
    int b = blockIdx.x >> P2_SH, p = blockIdx.x & (P2 - 1);
    for (int i = threadIdx.x; i < SBN_MAX; i += TPB) hsb[i] = 0;
    for (int i = threadIdx.x; i < CN; i += TPB) dcnt[i] = 0;
    __syncthreads();
    int lo = base[b], sz = base[b + 1] - lo;
    int i0 = lo + (int)((long long)sz * p / P2);
    int i1 = lo + (int)((long long)sz * (p + 1) / P2);
    int a0 = min(i1, (i0 + 3) & ~3);
    int a1 = a0 + ((i1 - a0) & ~3);
    for (int i = i0 + (int)threadIdx.x; i < a0; i += TPB) {   // head
        unsigned pk = packed[i];
        atomicAdd(&hsb[pk >> (CSH + SB_SH)], 1);
        atomicAdd(&dcnt[pk & (CN - 1)], 1);
    }
    for (int i = a0 + (int)threadIdx.x * 4; i < a1; i += TPB * 4) {  // body
        uint4 q = *(const uint4*)(packed + i);
        atomicAdd(&hsb[q.x >> (CSH + SB_SH)], 1); atomicAdd(&dcnt[q.x & (CN - 1)], 1);
        atomicAdd(&hsb[q.y >> (CSH + SB_SH)], 1); atomicAdd(&dcnt[q.y & (CN - 1)], 1);
        atomicAdd(&hsb[q.z >> (CSH + SB_SH)], 1); atomicAdd(&dcnt[q.z & (CN - 1)], 1);
        atomicAdd(&hsb[q.w >> (CSH + SB_SH)], 1); atomicAdd(&dcnt[q.w & (CN - 1)], 1);
    }
    for (int i = a1 + (int)threadIdx.x; i < i1; i += TPB) {   // tail
        unsigned pk = packed[i];
        atomicAdd(&hsb[pk >> (CSH + SB_SH)], 1);
        atomicAdd(&dcnt[pk & (CN - 1)], 1);
    }
    __syncthreads();
    int* hp = h + (size_t)blockIdx.x * SBN;
    for (int i2 = threadIdx.x; i2 < SBN; i2 += TPB) hp[i2] = hsb[i2];
    int node0 = b << CSH;
    for (int i2 = threadIdx.x; i2 < CN; i2 += TPB)
        if (dcnt[i2] && node0 + i2 < N) atomicAdd(&deg[node0 + i2], dcnt[i2]);
}

// in-place h -> exclusive cell bases, per bucket, (sb-major, p-minor) order
// => packed2 layout [bucket][src-block][p]: full-cell gather contiguity.
__global__ void k_scan3(int* __restrict__ h, const int* __restrict__ base, int SBN) {
    __shared__ int tsum[TPB];
    int b = blockIdx.x;
    int* hb = h + (size_t)b * P2 * SBN;
    int n = SBN * P2;                    // logical idx = sb*P2 + p
    int per = (n + TPB - 1) / TPB;       // <= 32
    int i0 = threadIdx.x * per;
    int vals[32];
    int sum = 0;
    for (int k = 0; k < per && k < 32; k++) {
        int idx = i0 + k;
        int v = 0;
        if (idx < n) {
            int sb = idx >> P2_SH, p = idx & (P2 - 1);
            v = hb[p * SBN + sb];
        }
        vals[k] = v;
        sum += v;
    }
    tsum[threadIdx.x] = sum;
    __syncthreads();
    for (int off = 1; off < TPB; off <<= 1) {
        int v = (threadIdx.x >= off) ? tsum[threadIdx.x - off] : 0;
        __syncthreads();
        tsum[threadIdx.x] += v;
        __syncthreads();
    }
    int run = base[b] + ((threadIdx.x == 0) ? 0 : tsum[threadIdx.x - 1]);
    for (int k = 0; k < per && k < 32; k++) {
        int idx = i0 + k;
        if (idx < n) {
            int sb = idx >> P2_SH, p = idx & (P2 - 1);
            hb[p * SBN + sb] = run;
            run += vals[k];
        }
    }
}

// stage 2b: LDS-STAGED cell scatter (R2-proven write pattern, amp 1.31 measured).
// Rank via LDS atomic; r<CAP stages into binbuf, r>=CAP (rare, Poisson tail)
// writes direct. End flush: wave-strided bursts => each output line written in
// one temporal cluster instead of trickled over the kernel lifetime (R4/R6's
// 4.3-4.6x write amp came from trickled 4B stores holding partial lines open).
// Dynamic LDS: goff[SBN] | cnt2[SBN] | binbuf[SBN*CAP]  (~34 KB at SBN=391).
__global__ void k_p2scat(const unsigned* __restrict__ packed, const int* __restrict__ base,
                         const int* __restrict__ h, unsigned* __restrict__ packed2,
                         int SBN) {
    extern __shared__ int dsm[];
    int* goff = dsm;
    int* cnt2 = dsm + SBN;
    unsigned* binbuf = (unsigned*)(dsm + 2 * SBN);
    int b = blockIdx.x >> P2_SH, p = blockIdx.x & (P2 - 1);
    const int* hp = h + (size_t)blockIdx.x * SBN;
    for (int i = threadIdx.x; i < SBN; i += TPB) {
        cnt2[i] = 0;
        goff[i] = hp[i];
    }
    __syncthreads();
    int lo = base[b], sz = base[b + 1] - lo;
    int i0 = lo + (int)((long long)sz * p / P2);
    int i1 = lo + (int)((long long)sz * (p + 1) / P2);
    int a0 = min(i1, (i0 + 3) & ~3);
    int a1 = a0 + ((i1 - a0) & ~3);
    for (int i = i0 + (int)threadIdx.x; i < a0; i += TPB) {   // head
        unsigned pk = packed[i];
        int sb2 = pk >> (CSH + SB_SH);
        int r = atomicAdd(&cnt2[sb2], 1);
        if (r < CAP) binbuf[sb2 * CAP + r] = pk;
        else packed2[goff[sb2] + r] = pk;
    }
    for (int i = a0 + (int)threadIdx.x * 4; i < a1; i += TPB * 4) {  // body
        uint4 q = *(const uint4*)(packed + i);
        int sa = q.x >> (CSH + SB_SH), sb_ = q.y >> (CSH + SB_SH);
        int sc = q.z >> (CSH + SB_SH), sd = q.w >> (CSH + SB_SH);
        int ra = atomicAdd(&cnt2[sa], 1);      // 4 independent rank chains
        int rb = atomicAdd(&cnt2[sb_], 1);
        int rc = atomicAdd(&cnt2[sc], 1);
        int rd = atomicAdd(&cnt2[sd], 1);
        if (ra < CAP) binbuf[sa * CAP + ra] = q.x; else packed2[goff[sa] + ra] = q.x;
        if (rb < CAP) binbuf[sb_ * CAP + rb] = q.y; else packed2[goff[sb_] + rb] = q.y;
        if (rc < CAP) binbuf[sc * CAP + rc] = q.z; else packed2[goff[sc] + rc] = q.z;
        if (rd < CAP) binbuf[sd * CAP + rd] = q.w; else packed2[goff[sd] + rd] = q.w;
    }
    for (int i = a1 + (int)threadIdx.x; i < i1; i += TPB) {   // tail
        unsigned pk = packed[i];
        int sb2 = pk >> (CSH + SB_SH);
        int r = atomicAdd(&cnt2[sb2], 1);
        if (r < CAP) binbuf[sb2 * CAP + r] = pk;
        else packed2[goff[sb2] + r] = pk;
    }
    __syncthreads();
    int wv = threadIdx.x >> 6, lane = threadIdx.x & 63;
    for (int sb2 = wv; sb2 < SBN; sb2 += 4) {   // burst flush
        int c = min(cnt2[sb2], CAP);
        if (!c) continue;
        int gb = goff[sb2];
        for (int i = lane; i < c; i += 64)
            packed2[gb + i] = binbuf[sb2 * CAP + i];
    }
}

// xs = x * rsqrt(deg+1) (float4 self-term) and encoded uint4 for gathers
__global__ void k_prepv(const float* __restrict__ x, const int* __restrict__ deg,
                        float* __restrict__ xs, unsigned* __restrict__ xse, int N) {
    int v = blockIdx.x * blockDim.x + threadIdx.x;
    if (v >= N) return;
    float di = rsqrtf((float)(deg[v] + 1));
    float4 xv = ((const float4*)x)[v];
    xv.x *= di; xv.y *= di; xv.z *= di; xv.w *= di;
    ((float4*)xs)[v] = xv;
    uint4 e;
    e.x = enc_fx(xv.x, S1F); e.y = enc_fx(xv.y, S1F);
    e.z = enc_fx(xv.z, S1F); e.w = enc_fx(xv.w, S1F);
    ((uint4*)xse)[v] = e;
}

#define AGG1_AT(pkv, gv) { int n_ = (int)((pkv) & (CN - 1)) * 3; \
    atomicAdd(&acc[n_],     (u64)(gv).x | ((u64)(gv).y << 32)); \
    atomicAdd(&acc[n_ + 1], (u64)(gv).z | ((u64)(gv).w << 32)); }

// layer-1 edge pass: contiguous stream over src-sorted packed2 (R2/R4-proven)
__global__ void k_agg1n(const unsigned* __restrict__ packed2, const int* __restrict__ base,
                        const unsigned* __restrict__ xse, u64* __restrict__ partial1, int S1) {
    __shared__ u64 acc[CN * 3];   // stride 3 u64 to spread banks; 24 KB
    for (int i = threadIdx.x; i < CN * 3; i += TPB) acc[i] = 0ULL;
    __syncthreads();
    int b = blockIdx.x / S1, s = blockIdx.x - b * S1;
    int lo = base[b], sz = base[b + 1] - lo;
    int i0 = lo + (int)((long long)sz * s / S1);
    int i1 = lo + (int)((long long)sz * (s + 1) / S1);
    const uint4* xse4 = (const uint4*)xse;
    int i = i0 + (int)threadIdx.x;
    for (; i + 3 * TPB < i1; i += 4 * TPB) {
        unsigned pa = packed2[i];
        unsigned pb = packed2[i + TPB];
        unsigned pc = packed2[i + 2 * TPB];
        unsigned pd = packed2[i + 3 * TPB];
        uint4 ga = xse4[pa >> CSH];
        uint4 gb = xse4[pb >> CSH];
        uint4 gc = xse4[pc >> CSH];
        uint4 gd = xse4[pd >> CSH];
        AGG1_AT(pa, ga); AGG1_AT(pb, gb); AGG1_AT(pc, gc); AGG1_AT(pd, gd);
    }
    for (; i < i1; i += TPB) {
        unsigned pk = packed2[i];
        uint4 g = xse4[pk >> CSH];
        AGG1_AT(pk, g);
    }
    __syncthreads();
    u64* p = partial1 + (size_t)blockIdx.x * (CN * 2);
    for (int i2 = threadIdx.x; i2 < CN * 2; i2 += TPB)
        p[i2] = acc[(i2 >> 1) * 3 + (i2 & 1)];
}

// layer-1 combine: decode fixed-point, +self, *dis -> MLP -> hs2 (float + encoded)
__global__ void k_comb1q(const u64* __restrict__ partial1,
                         const float* __restrict__ xs, const int* __restrict__ deg,
                         const float* __restrict__ W1, const float* __restrict__ b1,
                         const float* __restrict__ W2,
                         float* __restrict__ hs2f, unsigned* __restrict__ hs2e,
                         int S1, int N) {
    __shared__ float w1[64], w2[32], bb[16];
    if (threadIdx.x < 64) w1[threadIdx.x] = W1[threadIdx.x];
    if (threadIdx.x < 32) w2[threadIdx.x] = W2[threadIdx.x];
    if (threadIdx.x < 16) bb[threadIdx.x] = b1[threadIdx.x];
    __syncthreads();
    int v = blockIdx.x * blockDim.x + threadIdx.x;
    if (v >= N) return;
    int b = v >> CSH, lv = v & (CN - 1);
    u64 a01 = 0, a23 = 0;
    for (int s = 0; s < S1; s++) {
        const u64* q = partial1 + ((size_t)(b * S1 + s) * CN + lv) * 2;
        a01 += q[0];
        a23 += q[1];
    }
    int dg = deg[v];
    long long bias = (long long)dg << 20;
    const float inv = 1.0f / S1F;
    float f0 = (float)((long long)(a01 & 0xffffffffULL) - bias) * inv;
    float f1 = (float)((long long)(a01 >> 32) - bias) * inv;
    float f2 = (float)((long long)(a23 & 0xffffffffULL) - bias) * inv;
    float f3 = (float)((long long)(a23 >> 32) - bias) * inv;
    float4 self = ((const float4*)xs)[v];
    float di = rsqrtf((float)(dg + 1));
    float v0 = (f0 + self.x) * di, v1 = (f1 + self.y) * di;
    float v2 = (f2 + self.z) * di, v3 = (f3 + self.w) * di;
    float s0 = 0.f, s1 = 0.f;
#pragma unroll
    for (int j = 0; j < 16; j++) {
        float h = v0 * w1[j] + v1 * w1[16 + j] + v2 * w1[32 + j] + v3 * w1[48 + j] + bb[j];
        h = fmaxf(h, 0.0f);
        s0 += h * w2[2 * j];
        s1 += h * w2[2 * j + 1];
    }
    s0 *= di; s1 *= di;
    ((float2*)hs2f)[v] = make_float2(s0, s1);
    uint2 e;
    e.x = enc_fx(s0, S2F);
    e.y = enc_fx(s1, S2F);
    ((uint2*)hs2e)[v] = e;
}

// layer-2 edge pass: contiguous stream over src-sorted packed2 (R2/R4-proven)
__global__ void k_agg2n(const unsigned* __restrict__ packed2, const int* __restrict__ base,
                        const unsigned* __restrict__ hs2e, u64* __restrict__ partial2, int S2) {
    __shared__ u64 acc[CN];   // 8 KB
    for (int i = threadIdx.x; i < CN; i += TPB) acc[i] = 0ULL;
    __syncthreads();
    int b = blockIdx.x / S2, s = blockIdx.x - b * S2;
    int lo = base[b], sz = base[b + 1] - lo;
    int i0 = lo + (int)((long long)sz * s / S2);
    int i1 = lo + (int)((long long)sz * (s + 1) / S2);
    const uint2* h2 = (const uint2*)hs2e;
    int i = i0 + (int)threadIdx.x;
    for (; i + 3 * TPB < i1; i += 4 * TPB) {
        unsigned pa = packed2[i];
        unsigned pb = packed2[i + TPB];
        unsigned pc = packed2[i + 2 * TPB];
        unsigned pd = packed2[i + 3 * TPB];
        uint2 ga = h2[pa >> CSH];
        uint2 gb = h2[pb >> CSH];
        uint2 gc = h2[pc >> CSH];
        uint2 gd = h2[pd >> CSH];
        atomicAdd(&acc[pa & (CN - 1)], (u64)ga.x | ((u64)ga.y << 32));
        atomicAdd(&acc[pb & (CN - 1)], (u64)gb.x | ((u64)gb.y << 32));
        atomicAdd(&acc[pc & (CN - 1)], (u64)gc.x | ((u64)gc.y << 32));
        atomicAdd(&acc[pd & (CN - 1)], (u64)gd.x | ((u64)gd.y << 32));
    }
    for (; i < i1; i += TPB) {
        unsigned pk = packed2[i];
        uint2 g = h2[pk >> CSH];
        atomicAdd(&acc[pk & (CN - 1)], (u64)g.x | ((u64)g.y << 32));
    }
    __syncthreads();
    u64* p = partial2 + (size_t)blockIdx.x * CN;
    for (int i2 = threadIdx.x; i2 < CN; i2 += TPB) p[i2] = acc[i2];
}

// layer-2 combine: decode, +self, *dis, +bias -> out
__global__ void k_comb2q(const u64* __restrict__ partial2,
                         const float* __restrict__ hs2f, const int* __restrict__ deg,
                         const float* __restrict__ b2, float* __restrict__ out,
                         int S2, int N) {
    int v = blockIdx.x * blockDim.x + threadIdx.x;
    if (v >= N) return;
    int b = v >> CSH, lv = v & (CN - 1);
    u64 t = 0;
    for (int s = 0; s < S2; s++)
        t += partial2[(size_t)(b * S2 + s) * CN + lv];
    int dg = deg[v];
    long long bias = (long long)dg << 20;
    const float inv = 1.0f / S2F;
    float f0 = (float)((long long)(t & 0xffffffffULL) - bias) * inv;
    float f1 = (float)((long long)(t >> 32) - bias) * inv;
    float2 self = ((const float2*)hs2f)[v];
    float di = rsqrtf((float)(dg + 1));
    ((float2*)out)[v] = make_float2((f0 + self.x) * di + b2[0],
                                    (f1 + self.y) * di + b2[1]);
}

// ---------------- fallback (R1 atomic pipeline) ----------------

__global__ void k_zero(int* __restrict__ p, int n) {
    int i = blockIdx.x * blockDim.x + threadIdx.x;
    if (i < n) p[i] = 0;
}
__global__ void k_deg_fb(const int* __restrict__ dst, int* __restrict__ deg, int E) {
    int i = blockIdx.x * blockDim.x + threadIdx.x;
    if (i < E) atomicAdd(&deg[dst[i]], 1);
}
__global__ void k_dis_fb(const int* __restrict__ deg, float* __restrict__ dis, int N) {
    int v = blockIdx.x * blockDim.x + threadIdx.x;
    if (v < N) dis[v] = rsqrtf((float)(deg[v] + 1));
}
__global__ void k_lin1_fb(const float* __restrict__ x, const float* __restrict__ W1,
                          const float* __restrict__ dis, float* __restrict__ hs1,
                          float* __restrict__ agg1, int N) {
    __shared__ float w[64];
    if (threadIdx.x < 64) w[threadIdx.x] = W1[threadIdx.x];
    __syncthreads();
    int v = blockIdx.x * blockDim.x + threadIdx.x;
    if (v >= N) return;
    float4 xv = ((const float4*)x)[v];
    float d = dis[v];
#pragma unroll
    for (int j = 0; j < 16; j++) {
        float h = (xv.x * w[j] + xv.y * w[16 + j] + xv.z * w[32 + j] + xv.w * w[48 + j]) * d;
        hs1[v * 16 + j] = h;
        agg1[v * 16 + j] = h;
    }
}
__global__ void k_scat1_fb(const int* __restrict__ src, const int* __restrict__ dst,
                           const float* __restrict__ hs1, float* __restrict__ agg1, int E4) {
    int t = blockIdx.x * blockDim.x + threadIdx.x;
    if (t >= E4) return;
    int e = t >> 2, q = t & 3;
    int s = src[e], d = dst[e];
    float4 m = ((const float4*)hs1)[s * 4 + q];
    float* a = agg1 + (size_t)d * 16 + q * 4;
    atomicAdd(a + 0, m.x); atomicAdd(a + 1, m.y);
    atomicAdd(a + 2, m.z); atomicAdd(a + 3, m.w);
}
__global__ void k_lin2_fb(const float* __restrict__ agg1, const float* __restrict__ dis,
                          const float* __restrict__ b1, const float* __restrict__ W2,
                          float* __restrict__ hs2, float* __restrict__ agg2, int N) {
    __shared__ float w[32];
    __shared__ float bb[16];
    if (threadIdx.x < 32) w[threadIdx.x] = W2[threadIdx.x];
    if (threadIdx.x < 16) bb[threadIdx.x] = b1[threadIdx.x];
    __syncthreads();
    int v = blockIdx.x * blockDim.x + threadIdx.x;
    if (v >= N) return;
    float d = dis[v];
    float a0 = 0.f, a1 = 0.f;
#pragma unroll
    for (int k = 0; k < 16; k++) {
        float r = fmaxf(agg1[v * 16 + k] * d + bb[k], 0.0f);
        a0 += r * w[k * 2 + 0];
        a1 += r * w[k * 2 + 1];
    }
    float2 hv = make_float2(a0 * d, a1 * d);
    ((float2*)hs2)[v] = hv;
    ((float2*)agg2)[v] = hv;
}
__global__ void k_scat2_fb(const int* __restrict__ src, const int* __restrict__ dst,
                           const float* __restrict__ hs2, float* __restrict__ agg2, int E) {
    int e = blockIdx.x * blockDim.x + threadIdx.x;
    if (e >= E) return;
    int s = src[e], d = dst[e];
    float2 m = ((const float2*)hs2)[s];
    atomicAdd(&agg2[d * 2 + 0], m.x);
    atomicAdd(&agg2[d * 2 + 1], m.y);
}
__global__ void k_out_fb(const float* __restrict__ agg2, const float* __restrict__ dis,
                         const float* __restrict__ b2, float* __restrict__ out, int N) {
    int v = blockIdx.x * blockDim.x + threadIdx.x;
    if (v >= N) return;
    float d = dis[v];
    out[v * 2 + 0] = agg2[v * 2 + 0] * d + b2[0];
    out[v * 2 + 1] = agg2[v * 2 + 1] * d + b2[1];
}

// ---------------- launch ----------------

extern "C" void kernel_launch(void* const* d_in, const int* in_sizes, int n_in,
                              void* d_out, int out_size, void* d_ws, size_t ws_size,
                              hipStream_t stream) {
    const float* x  = (const float*)d_in[0];
    const int*   ei = (const int*)d_in[1];
    const float* W1 = (const float*)d_in[2];
    const float* b1 = (const float*)d_in[3];
    const float* W2 = (const float*)d_in[4];
    const float* b2 = (const float*)d_in[5];

    const int N = in_sizes[0] / 4;
    const int E = in_sizes[1] / 2;
    const int* src = ei;
    const int* dst = ei + E;
    float* outp = (float*)d_out;

    auto align = [](size_t v) { return (v + 255) & ~(size_t)255; };
    const int NBC = (N + CN - 1) >> CSH;              // 98
    const int SBN = (N + (1 << SB_SH) - 1) >> SB_SH;  // 391
    const int NC  = NBC * P2 * SBN;                   // h entries
    const int gN  = (N + TPB - 1) / TPB;
    const int ntiles = (E + STILE - 1) / STILE;       // 1563
    const bool src_fits = (size_t)N <= ((size_t)1 << (32 - CSH));
    const bool fx_safe = (long long)E <= (long long)N * 512;

    const int S1 = 16, S2 = 16;
    size_t part1_bytes = (size_t)NBC * S1 * CN * 16;
    size_t part2_bytes = (size_t)NBC * S2 * CN * 8;
    size_t pkA_bytes = (size_t)E * 4;                 // packed, later partial1/2
    if (part1_bytes > pkA_bytes) pkA_bytes = part1_bytes;
    if (part2_bytes > pkA_bytes) pkA_bytes = part2_bytes;

    size_t need_new = align(pkA_bytes)                   /* packed / partial1 / partial2 */
                    + align((size_t)E * 4)               /* packed2 */
                    + align((size_t)N * 16)              /* xs */
                    + align((size_t)N * 16)              /* xse */
                    + align((size_t)N * 8)               /* hs2f */
                    + align((size_t)N * 8)               /* hs2e */
                    + align((size_t)N * 4)               /* deg */
                    + align((size_t)NC * 4)              /* h */
                    + align((size_t)NBC * 4)             /* hist0 */
                    + align((size_t)NBC * 4)             /* cur */
                    + align((size_t)(NBC + 1) * 4);      /* base */

    const size_t p2s_smem = (size_t)SBN * (2 + CAP) * 4; // goff|cnt2|binbuf ~34 KB

    if (ws_size >= need_new && NBC <= NBC_MAX && SBN <= SBN_MAX && src_fits && fx_safe) {
        char* ws = (char*)d_ws;
        unsigned* packed = (unsigned*)ws;   // dead after p2scat
        u64* partial1 = (u64*)ws;           // aliased: live agg1n..comb1q
        u64* partial2 = (u64*)ws;           // aliased: live agg2n..comb2q
        ws += align(pkA_bytes);
        unsigned* packed2 = (unsigned*)ws; ws += align((size_t)E * 4);
        float* xs    = (float*)ws;    ws += align((size_t)N * 16);
        unsigned* xse = (unsigned*)ws; ws += align((size_t)N * 16);
        float* hs2f  = (float*)ws;    ws += align((size_t)N * 8);
        unsigned* hs2e = (unsigned*)ws; ws += align((size_t)N * 8);
        int* deg     = (int*)ws;      ws += align((size_t)N * 4);
        int* h       = (int*)ws;      ws += align((size_t)NC * 4);
        int* hist0   = (int*)ws;      ws += align((size_t)NBC * 4);
        int* cur     = (int*)ws;      ws += align((size_t)NBC * 4);
        int* base    = (int*)ws;      ws += align((size_t)(NBC + 1) * 4);

        k_zero2<<<gN, TPB, 0, stream>>>(deg, N, hist0, NBC);
        k_hist0<<<1024, TPB, 0, stream>>>(dst, hist0, NBC, E);
        k_scanbase<<<1, TPB, 0, stream>>>(hist0, base, cur, NBC);
        k_bscat<<<ntiles, TPB, 0, stream>>>(src, dst, cur, packed, E, NBC);
        k_p2hist<<<NBC * P2, TPB, 0, stream>>>(packed, base, h, deg, SBN, N);
        k_scan3<<<NBC, TPB, 0, stream>>>(h, base, SBN);
        k_p2scat<<<NBC * P2, TPB, p2s_smem, stream>>>(packed, base, h, packed2, SBN);
        k_prepv<<<gN, TPB, 0, stream>>>(x, deg, xs, xse, N);
        k_agg1n<<<NBC * S1, TPB, 0, stream>>>(packed2, base, xse, partial1, S1);
        k_comb1q<<<gN, TPB, 0, stream>>>(partial1, xs, deg, W1, b1, W2, hs2f, hs2e, S1, N);
        k_agg2n<<<NBC * S2, TPB, 0, stream>>>(packed2, base, hs2e, partial2, S2);
        k_comb2q<<<gN, TPB, 0, stream>>>(partial2, hs2f, deg, b2, outp, S2, N);
    } else {
        // fallback: R1 atomic-scatter pipeline
        char* ws = (char*)d_ws;
        int*   deg  = (int*)ws;   ws += align((size_t)N * 4);
        float* dis  = (float*)ws; ws += align((size_t)N * 4);
        float* hs1  = (float*)ws; ws += align((size_t)N * 16 * 4);
        float* agg1 = (float*)ws; ws += align((size_t)N * 16 * 4);
        float* hs2  = (float*)ws; ws += align((size_t)N * 2 * 4);
        float* agg2 = (float*)ws; ws += align((size_t)N * 2 * 4);
        int gE = (E + TPB - 1) / TPB;
        int gE4 = ((size_t)E * 4 + TPB - 1) / TPB;

        k_zero<<<gN, TPB, 0, stream>>>(deg, N);
        k_deg_fb<<<gE, TPB, 0, stream>>>(dst, deg, E);
        k_dis_fb<<<gN, TPB, 0, stream>>>(deg, dis, N);
        k_lin1_fb<<<gN, TPB, 0, stream>>>(x, W1, dis, hs1, agg1, N);
        k_scat1_fb<<<gE4, TPB, 0, stream>>>(src, dst, hs1, agg1, E * 4);
        k_lin2_fb<<<gN, TPB, 0, stream>>>(agg1, dis, b1, W2, hs2, agg2, N);
        k_scat2_fb<<<gE, TPB, 0, stream>>>(src, dst, hs2, agg2, E);
        k_out_fb<<<gN, TPB, 0, stream>>>(agg2, dis, b2, outp, N);
    }
}

// Round 8
// 256.075 us; speedup vs baseline: 1.8675x; 1.0093x over previous
//
#include <hip/hip_runtime.h>

#define TPB 256
#define CSH 10                 // nodes per dst bucket = 1024
#define CN 1024
#define NBC_MAX 128
#define STILE 4096             // bscat tile (16 KB stage -> 8 blocks/CU)
#define EPT (STILE / TPB)      // 16

#define P2 16                  // stage-2 blocks per bucket
#define P2_SH 4
#define SB_SH 8                // src-block granularity = 256 nodes
#define SBN_MAX 512            // max src-blocks (N <= 131072)
#define CAP 20                 // p2scat staged entries per bin (mean ~10.7)

// fixed-point packing: value -> (int)rn(v*SCALE) + BIAS, two per u64
#define B20 1048576            // bias 2^20
#define S1F 131072.0f          // layer-1 scale 2^17
#define S2F 8192.0f            // layer-2 scale 2^13

typedef unsigned long long u64;

__device__ __forceinline__ unsigned enc_fx(float v, float scale) {
    int xi = __float2int_rn(v * scale);
    xi = max(-(B20 - 1), min(B20 - 1, xi));
    return (unsigned)(xi + B20);
}

__global__ void k_zero2(int* __restrict__ a, int na, int* __restrict__ b, int nb) {
    int i = blockIdx.x * blockDim.x + threadIdx.x;
    if (i < na) a[i] = 0;
    if (i < nb) b[i] = 0;
}

// per-bucket edge counts (98 bins): LDS histogram, int4 reads, one flush atomic/bin
__global__ void k_hist0(const int* __restrict__ dst, int* __restrict__ hist0,
                        int NBC, int E) {
    __shared__ int hh[NBC_MAX];
    for (int i = threadIdx.x; i < NBC_MAX; i += TPB) hh[i] = 0;
    __syncthreads();
    int E4 = E >> 2;
    int stride = gridDim.x * blockDim.x;
    for (int i = blockIdx.x * blockDim.x + threadIdx.x; i < E4; i += stride) {
        int4 d4 = ((const int4*)dst)[i];
        atomicAdd(&hh[d4.x >> CSH], 1);
        atomicAdd(&hh[d4.y >> CSH], 1);
        atomicAdd(&hh[d4.z >> CSH], 1);
        atomicAdd(&hh[d4.w >> CSH], 1);
    }
    if (blockIdx.x == 0) {                     // tail E % 4
        for (int i = (E4 << 2) + (int)threadIdx.x; i < E; i += TPB)
            atomicAdd(&hh[dst[i] >> CSH], 1);
    }
    __syncthreads();
    for (int i = threadIdx.x; i < NBC; i += TPB)
        if (hh[i]) atomicAdd(&hist0[i], hh[i]);
}

// exclusive scan of bucket sizes -> base[0..NBC]; also init bulk-reserve cursors
__global__ void k_scanbase(const int* __restrict__ bsize, int* __restrict__ base,
                           int* __restrict__ cur, int NBC) {
    __shared__ int s[NBC_MAX];
    int t = threadIdx.x;
    if (t < NBC_MAX) s[t] = (t < NBC) ? bsize[t] : 0;
    __syncthreads();
    for (int off = 1; off < NBC_MAX; off <<= 1) {
        int v = 0;
        if (t < NBC_MAX && t >= off) v = s[t - off];
        __syncthreads();
        if (t < NBC_MAX) s[t] += v;
        __syncthreads();
    }
    if (t < NBC) {
        int b = (t == 0) ? 0 : s[t - 1];
        base[t] = b;
        cur[t] = b;
    }
    if (t == 0) base[NBC] = s[NBC - 1];
}

// stage 1: bucket scatter. In-LDS grouping by dst-bucket, per-bin BULK cursor
// reservation, wave-coalesced burst flush. R7 lesson: the serial per-thread
// prefix (`for j<b sum+=cnt[j]`, ~100 DEPENDENT LDS reads inside a barrier
// phase) was the per-block serial tax that made smaller tiles SLOWER. Replaced
// with a 7-step Hillis-Steele block scan. Loads int4-vectorized on full tiles.
__global__ void k_bscat(const int* __restrict__ src, const int* __restrict__ dst,
                        int* __restrict__ cur, unsigned* __restrict__ packed,
                        int E, int NBC) {
    __shared__ unsigned stage[STILE];          // 16 KB
    __shared__ int cnt[NBC_MAX], lb[NBC_MAX], resv[NBC_MAX];
    int tb = blockIdx.x * STILE;
    int te = min(E, tb + STILE);
    if (threadIdx.x < NBC_MAX) cnt[threadIdx.x] = 0;
    __syncthreads();
    unsigned pk[EPT];
    int br[EPT];   // bucket | rank<<7  (bucket < 128)
    bool vec = (te - tb == STILE) &&
               ((((size_t)(src + tb)) | ((size_t)(dst + tb))) & 15) == 0;
    if (vec) {
        const int4* s4 = (const int4*)(src + tb);
        const int4* d4 = (const int4*)(dst + tb);
#pragma unroll
        for (int u = 0; u < EPT / 4; u++) {
            int4 dd = d4[u * TPB + threadIdx.x];
            int4 ss = s4[u * TPB + threadIdx.x];
            int b0 = dd.x >> CSH, b1 = dd.y >> CSH, b2 = dd.z >> CSH, b3 = dd.w >> CSH;
            pk[4 * u + 0] = ((unsigned)ss.x << CSH) | (unsigned)(dd.x & (CN - 1));
            pk[4 * u + 1] = ((unsigned)ss.y << CSH) | (unsigned)(dd.y & (CN - 1));
            pk[4 * u + 2] = ((unsigned)ss.z << CSH) | (unsigned)(dd.z & (CN - 1));
            pk[4 * u + 3] = ((unsigned)ss.w << CSH) | (unsigned)(dd.w & (CN - 1));
            int r0 = atomicAdd(&cnt[b0], 1);
            int r1 = atomicAdd(&cnt[b1], 1);
            int r2 = atomicAdd(&cnt[b2], 1);
            int r3 = atomicAdd(&cnt[b3], 1);
            br[4 * u + 0] = b0 | (r0 << 7);
            br[4 * u + 1] = b1 | (r1 << 7);
            br[4 * u + 2] = b2 | (r2 << 7);
            br[4 * u + 3] = b3 | (r3 << 7);
        }
    } else {
#pragma unroll
        for (int u = 0; u < EPT; u++) {
            int i = tb + u * TPB + (int)threadIdx.x;
            br[u] = -1;
            if (i < te) {
                int d = dst[i];
                int b = d >> CSH;
                pk[u] = ((unsigned)src[i] << CSH) | (unsigned)(d & (CN - 1));
                int r = atomicAdd(&cnt[b], 1);
                br[u] = b | (r << 7);
            }
        }
    }
    __syncthreads();
    int t = threadIdx.x;
    if (t < NBC_MAX) lb[t] = cnt[t];           // parallel exclusive scan of cnt
    __syncthreads();
    for (int off = 1; off < NBC_MAX; off <<= 1) {
        int v = 0;
        if (t < NBC_MAX && t >= off) v = lb[t - off];
        __syncthreads();
        if (t < NBC_MAX) lb[t] += v;
        __syncthreads();
    }
    if (t < NBC_MAX) lb[t] -= cnt[t];          // inclusive -> exclusive (own slot)
    if (t < (unsigned)NBC) resv[t] = cnt[t] ? atomicAdd(&cur[t], cnt[t]) : 0;
    __syncthreads();
#pragma unroll
    for (int u = 0; u < EPT; u++) {
        if (br[u] >= 0) {
            int b = br[u] & (NBC_MAX - 1);
            stage[lb[b] + (br[u] >> 7)] = pk[u];
        }
    }
    __syncthreads();
    int wv = threadIdx.x >> 6, lane = threadIdx.x & 63;
    for (int b = wv; b < NBC; b += 4) {        // burst flush, coalesced
        int c = cnt[b];
        if (!c) continue;
        int gb = resv[b], s0 = lb[b];
        for (int i = lane; i < c; i += 64)
            packed[gb + i] = stage[s0 + i];
    }
}

// stage 2a: per (bucket, p) block reads its CONTIGUOUS slice (uint4-vectorized),
// histograms src-blocks (for the cell sort) and dst-nodes (degrees).
__global__ void k_p2hist(const unsigned* __restrict__ packed, const int* __restrict__ base,
                         int* __restrict__ h, int* __restrict__ deg, int SBN, int N) {
    __shared__ int hsb[SBN_MAX];
    __shared__ int dcnt[CN];
    int b = blockIdx.x >> P2_SH, p = blockIdx.x & (P2 - 1);
    for (int i = threadIdx.x; i < SBN_MAX; i += TPB) hsb[i] = 0;
    for (int i = threadIdx.x; i < CN; i += TPB) dcnt[i] = 0;
    __syncthreads();
    int lo = base[b], sz = base[b + 1] - lo;
    int i0 = lo + (int)((long long)sz * p / P2);
    int i1 = lo + (int)((long long)sz * (p + 1) / P2);
    int a0 = min(i1, (i0 + 3) & ~3);
    int a1 = a0 + ((i1 - a0) & ~3);
    for (int i = i0 + (int)threadIdx.x; i < a0; i += TPB) {   // head
        unsigned pk = packed[i];
        atomicAdd(&hsb[pk >> (CSH + SB_SH)], 1);
        atomicAdd(&dcnt[pk & (CN - 1)], 1);
    }
    for (int i = a0 + (int)threadIdx.x * 4; i < a1; i += TPB * 4) {  // body
        uint4 q = *(const uint4*)(packed + i);
        atomicAdd(&hsb[q.x >> (CSH + SB_SH)], 1); atomicAdd(&dcnt[q.x & (CN - 1)], 1);
        atomicAdd(&hsb[q.y >> (CSH + SB_SH)], 1); atomicAdd(&dcnt[q.y & (CN - 1)], 1);
        atomicAdd(&hsb[q.z >> (CSH + SB_SH)], 1); atomicAdd(&dcnt[q.z & (CN - 1)], 1);
        atomicAdd(&hsb[q.w >> (CSH + SB_SH)], 1); atomicAdd(&dcnt[q.w & (CN - 1)], 1);
    }
    for (int i = a1 + (int)threadIdx.x; i < i1; i += TPB) {   // tail
        unsigned pk = packed[i];
        atomicAdd(&hsb[pk >> (CSH + SB_SH)], 1);
        atomicAdd(&dcnt[pk & (CN - 1)], 1);
    }
    __syncthreads();
    int* hp = h + (size_t)blockIdx.x * SBN;
    for (int i2 = threadIdx.x; i2 < SBN; i2 += TPB) hp[i2] = hsb[i2];
    int node0 = b << CSH;
    for (int i2 = threadIdx.x; i2 < CN; i2 += TPB)
        if (dcnt[i2] && node0 + i2 < N) atomicAdd(&deg[node0 + i2], dcnt[i2]);
}

// in-place h -> exclusive cell bases, per bucket, (sb-major, p-minor) order
// => packed2 layout [bucket][src-block][p]: full-cell gather contiguity.
__global__ void k_scan3(int* __restrict__ h, const int* __restrict__ base, int SBN) {
    __shared__ int tsum[TPB];
    int b = blockIdx.x;
    int* hb = h + (size_t)b * P2 * SBN;
    int n = SBN * P2;                    // logical idx = sb*P2 + p
    int per = (n + TPB - 1) / TPB;       // <= 32
    int i0 = threadIdx.x * per;
    int vals[32];
    int sum = 0;
    for (int k = 0; k < per && k < 32; k++) {
        int idx = i0 + k;
        int v = 0;
        if (idx < n) {
            int sb = idx >> P2_SH, p = idx & (P2 - 1);
            v = hb[p * SBN + sb];
        }
        vals[k] = v;
        sum += v;
    }
    tsum[threadIdx.x] = sum;
    __syncthreads();
    for (int off = 1; off < TPB; off <<= 1) {
        int v = (threadIdx.x >= off) ? tsum[threadIdx.x - off] : 0;
        __syncthreads();
        tsum[threadIdx.x] += v;
        __syncthreads();
    }
    int run = base[b] + ((threadIdx.x == 0) ? 0 : tsum[threadIdx.x - 1]);
    for (int k = 0; k < per && k < 32; k++) {
        int idx = i0 + k;
        if (idx < n) {
            int sb = idx >> P2_SH, p = idx & (P2 - 1);
            hb[p * SBN + sb] = run;
            run += vals[k];
        }
    }
}

// stage 2b: LDS-STAGED cell scatter (R7-verified: burst flush fixed the 4.3x
// write amp from trickled 4B stores). Rank via LDS atomic; r<CAP stages,
// r>=CAP (Poisson tail) writes direct. End flush: wave-strided bursts.
__global__ void k_p2scat(const unsigned* __restrict__ packed, const int* __restrict__ base,
                         const int* __restrict__ h, unsigned* __restrict__ packed2,
                         int SBN) {
    extern __shared__ int dsm[];
    int* goff = dsm;
    int* cnt2 = dsm + SBN;
    unsigned* binbuf = (unsigned*)(dsm + 2 * SBN);
    int b = blockIdx.x >> P2_SH, p = blockIdx.x & (P2 - 1);
    const int* hp = h + (size_t)blockIdx.x * SBN;
    for (int i = threadIdx.x; i < SBN; i += TPB) {
        cnt2[i] = 0;
        goff[i] = hp[i];
    }
    __syncthreads();
    int lo = base[b], sz = base[b + 1] - lo;
    int i0 = lo + (int)((long long)sz * p / P2);
    int i1 = lo + (int)((long long)sz * (p + 1) / P2);
    int a0 = min(i1, (i0 + 3) & ~3);
    int a1 = a0 + ((i1 - a0) & ~3);
    for (int i = i0 + (int)threadIdx.x; i < a0; i += TPB) {   // head
        unsigned pk = packed[i];
        int sb2 = pk >> (CSH + SB_SH);
        int r = atomicAdd(&cnt2[sb2], 1);
        if (r < CAP) binbuf[sb2 * CAP + r] = pk;
        else packed2[goff[sb2] + r] = pk;
    }
    for (int i = a0 + (int)threadIdx.x * 4; i < a1; i += TPB * 4) {  // body
        uint4 q = *(const uint4*)(packed + i);
        int sa = q.x >> (CSH + SB_SH), sb_ = q.y >> (CSH + SB_SH);
        int sc = q.z >> (CSH + SB_SH), sd = q.w >> (CSH + SB_SH);
        int ra = atomicAdd(&cnt2[sa], 1);      // 4 independent rank chains
        int rb = atomicAdd(&cnt2[sb_], 1);
        int rc = atomicAdd(&cnt2[sc], 1);
        int rd = atomicAdd(&cnt2[sd], 1);
        if (ra < CAP) binbuf[sa * CAP + ra] = q.x; else packed2[goff[sa] + ra] = q.x;
        if (rb < CAP) binbuf[sb_ * CAP + rb] = q.y; else packed2[goff[sb_] + rb] = q.y;
        if (rc < CAP) binbuf[sc * CAP + rc] = q.z; else packed2[goff[sc] + rc] = q.z;
        if (rd < CAP) binbuf[sd * CAP + rd] = q.w; else packed2[goff[sd] + rd] = q.w;
    }
    for (int i = a1 + (int)threadIdx.x; i < i1; i += TPB) {   // tail
        unsigned pk = packed[i];
        int sb2 = pk >> (CSH + SB_SH);
        int r = atomicAdd(&cnt2[sb2], 1);
        if (r < CAP) binbuf[sb2 * CAP + r] = pk;
        else packed2[goff[sb2] + r] = pk;
    }
    __syncthreads();
    int wv = threadIdx.x >> 6, lane = threadIdx.x & 63;
    for (int sb2 = wv; sb2 < SBN; sb2 += 4) {   // burst flush
        int c = min(cnt2[sb2], CAP);
        if (!c) continue;
        int gb = goff[sb2];
        for (int i = lane; i < c; i += 64)
            packed2[gb + i] = binbuf[sb2 * CAP + i];
    }
}

// xs = x * rsqrt(deg+1) (float4 self-term) and encoded uint4 for gathers
__global__ void k_prepv(const float* __restrict__ x, const int* __restrict__ deg,
                        float* __restrict__ xs, unsigned* __restrict__ xse, int N) {
    int v = blockIdx.x * blockDim.x + threadIdx.x;
    if (v >= N) return;
    float di = rsqrtf((float)(deg[v] + 1));
    float4 xv = ((const float4*)x)[v];
    xv.x *= di; xv.y *= di; xv.z *= di; xv.w *= di;
    ((float4*)xs)[v] = xv;
    uint4 e;
    e.x = enc_fx(xv.x, S1F); e.y = enc_fx(xv.y, S1F);
    e.z = enc_fx(xv.z, S1F); e.w = enc_fx(xv.w, S1F);
    ((uint4*)xse)[v] = e;
}

#define AGG1_AT(pkv, gv) { int n_ = (int)((pkv) & (CN - 1)) * 3; \
    atomicAdd(&acc[n_],     (u64)(gv).x | ((u64)(gv).y << 32)); \
    atomicAdd(&acc[n_ + 1], (u64)(gv).z | ((u64)(gv).w << 32)); }

// layer-1 edge pass: uint4 stream over cell-sorted packed2. A thread's 4 edges
// are consecutive => same cell => gathers often share a 64B line (L1-friendly).
__global__ void k_agg1n(const unsigned* __restrict__ packed2, const int* __restrict__ base,
                        const unsigned* __restrict__ xse, u64* __restrict__ partial1, int S1) {
    __shared__ u64 acc[CN * 3];   // stride 3 u64 to spread banks; 24 KB
    for (int i = threadIdx.x; i < CN * 3; i += TPB) acc[i] = 0ULL;
    __syncthreads();
    int b = blockIdx.x / S1, s = blockIdx.x - b * S1;
    int lo = base[b], sz = base[b + 1] - lo;
    int i0 = lo + (int)((long long)sz * s / S1);
    int i1 = lo + (int)((long long)sz * (s + 1) / S1);
    const uint4* xse4 = (const uint4*)xse;
    int a0 = min(i1, (i0 + 3) & ~3);
    int a1 = a0 + ((i1 - a0) & ~3);
    for (int i = i0 + (int)threadIdx.x; i < a0; i += TPB) {   // head
        unsigned pk = packed2[i];
        uint4 g = xse4[pk >> CSH];
        AGG1_AT(pk, g);
    }
    for (int i = a0 + (int)threadIdx.x * 4; i < a1; i += TPB * 4) {  // body
        uint4 q = *(const uint4*)(packed2 + i);
        uint4 ga = xse4[q.x >> CSH];
        uint4 gb = xse4[q.y >> CSH];
        uint4 gc = xse4[q.z >> CSH];
        uint4 gd = xse4[q.w >> CSH];
        AGG1_AT(q.x, ga); AGG1_AT(q.y, gb); AGG1_AT(q.z, gc); AGG1_AT(q.w, gd);
    }
    for (int i = a1 + (int)threadIdx.x; i < i1; i += TPB) {   // tail
        unsigned pk = packed2[i];
        uint4 g = xse4[pk >> CSH];
        AGG1_AT(pk, g);
    }
    __syncthreads();
    u64* p = partial1 + (size_t)blockIdx.x * (CN * 2);
    for (int i2 = threadIdx.x; i2 < CN * 2; i2 += TPB)
        p[i2] = acc[(i2 >> 1) * 3 + (i2 & 1)];
}

// layer-1 combine: decode fixed-point, +self, *dis -> MLP -> hs2 (float + encoded)
__global__ void k_comb1q(const u64* __restrict__ partial1,
                         const float* __restrict__ xs, const int* __restrict__ deg,
                         const float* __restrict__ W1, const float* __restrict__ b1,
                         const float* __restrict__ W2,
                         float* __restrict__ hs2f, unsigned* __restrict__ hs2e,
                         int S1, int N) {
    __shared__ float w1[64], w2[32], bb[16];
    if (threadIdx.x < 64) w1[threadIdx.x] = W1[threadIdx.x];
    if (threadIdx.x < 32) w2[threadIdx.x] = W2[threadIdx.x];
    if (threadIdx.x < 16) bb[threadIdx.x] = b1[threadIdx.x];
    __syncthreads();
    int v = blockIdx.x * blockDim.x + threadIdx.x;
    if (v >= N) return;
    int b = v >> CSH, lv = v & (CN - 1);
    u64 a01 = 0, a23 = 0;
    for (int s = 0; s < S1; s++) {
        const u64* q = partial1 + ((size_t)(b * S1 + s) * CN + lv) * 2;
        a01 += q[0];
        a23 += q[1];
    }
    int dg = deg[v];
    long long bias = (long long)dg << 20;
    const float inv = 1.0f / S1F;
    float f0 = (float)((long long)(a01 & 0xffffffffULL) - bias) * inv;
    float f1 = (float)((long long)(a01 >> 32) - bias) * inv;
    float f2 = (float)((long long)(a23 & 0xffffffffULL) - bias) * inv;
    float f3 = (float)((long long)(a23 >> 32) - bias) * inv;
    float4 self = ((const float4*)xs)[v];
    float di = rsqrtf((float)(dg + 1));
    float v0 = (f0 + self.x) * di, v1 = (f1 + self.y) * di;
    float v2 = (f2 + self.z) * di, v3 = (f3 + self.w) * di;
    float s0 = 0.f, s1 = 0.f;
#pragma unroll
    for (int j = 0; j < 16; j++) {
        float h = v0 * w1[j] + v1 * w1[16 + j] + v2 * w1[32 + j] + v3 * w1[48 + j] + bb[j];
        h = fmaxf(h, 0.0f);
        s0 += h * w2[2 * j];
        s1 += h * w2[2 * j + 1];
    }
    s0 *= di; s1 *= di;
    ((float2*)hs2f)[v] = make_float2(s0, s1);
    uint2 e;
    e.x = enc_fx(s0, S2F);
    e.y = enc_fx(s1, S2F);
    ((uint2*)hs2e)[v] = e;
}

// layer-2 edge pass: uint4 stream over cell-sorted packed2
__global__ void k_agg2n(const unsigned* __restrict__ packed2, const int* __restrict__ base,
                        const unsigned* __restrict__ hs2e, u64* __restrict__ partial2, int S2) {
    __shared__ u64 acc[CN];   // 8 KB
    for (int i = threadIdx.x; i < CN; i += TPB) acc[i] = 0ULL;
    __syncthreads();
    int b = blockIdx.x / S2, s = blockIdx.x - b * S2;
    int lo = base[b], sz = base[b + 1] - lo;
    int i0 = lo + (int)((long long)sz * s / S2);
    int i1 = lo + (int)((long long)sz * (s + 1) / S2);
    const uint2* h2 = (const uint2*)hs2e;
    int a0 = min(i1, (i0 + 3) & ~3);
    int a1 = a0 + ((i1 - a0) & ~3);
    for (int i = i0 + (int)threadIdx.x; i < a0; i += TPB) {   // head
        unsigned pk = packed2[i];
        uint2 g = h2[pk >> CSH];
        atomicAdd(&acc[pk & (CN - 1)], (u64)g.x | ((u64)g.y << 32));
    }
    for (int i = a0 + (int)threadIdx.x * 4; i < a1; i += TPB * 4) {  // body
        uint4 q = *(const uint4*)(packed2 + i);
        uint2 ga = h2[q.x >> CSH];
        uint2 gb = h2[q.y >> CSH];
        uint2 gc = h2[q.z >> CSH];
        uint2 gd = h2[q.w >> CSH];
        atomicAdd(&acc[q.x & (CN - 1)], (u64)ga.x | ((u64)ga.y << 32));
        atomicAdd(&acc[q.y & (CN - 1)], (u64)gb.x | ((u64)gb.y << 32));
        atomicAdd(&acc[q.z & (CN - 1)], (u64)gc.x | ((u64)gc.y << 32));
        atomicAdd(&acc[q.w & (CN - 1)], (u64)gd.x | ((u64)gd.y << 32));
    }
    for (int i = a1 + (int)threadIdx.x; i < i1; i += TPB) {   // tail
        unsigned pk = packed2[i];
        uint2 g = h2[pk >> CSH];
        atomicAdd(&acc[pk & (CN - 1)], (u64)g.x | ((u64)g.y << 32));
    }
    __syncthreads();
    u64* p = partial2 + (size_t)blockIdx.x * CN;
    for (int i2 = threadIdx.x; i2 < CN; i2 += TPB) p[i2] = acc[i2];
}

// layer-2 combine: decode, +self, *dis, +bias -> out
__global__ void k_comb2q(const u64* __restrict__ partial2,
                         const float* __restrict__ hs2f, const int* __restrict__ deg,
                         const float* __restrict__ b2, float* __restrict__ out,
                         int S2, int N) {
    int v = blockIdx.x * blockDim.x + threadIdx.x;
    if (v >= N) return;
    int b = v >> CSH, lv = v & (CN - 1);
    u64 t = 0;
    for (int s = 0; s < S2; s++)
        t += partial2[(size_t)(b * S2 + s) * CN + lv];
    int dg = deg[v];
    long long bias = (long long)dg << 20;
    const float inv = 1.0f / S2F;
    float f0 = (float)((long long)(t & 0xffffffffULL) - bias) * inv;
    float f1 = (float)((long long)(t >> 32) - bias) * inv;
    float2 self = ((const float2*)hs2f)[v];
    float di = rsqrtf((float)(dg + 1));
    ((float2*)out)[v] = make_float2((f0 + self.x) * di + b2[0],
                                    (f1 + self.y) * di + b2[1]);
}

// ---------------- fallback (R1 atomic pipeline) ----------------

__global__ void k_zero(int* __restrict__ p, int n) {
    int i = blockIdx.x * blockDim.x + threadIdx.x;
    if (i < n) p[i] = 0;
}
__global__ void k_deg_fb(const int* __restrict__ dst, int* __restrict__ deg, int E) {
    int i = blockIdx.x * blockDim.x + threadIdx.x;
    if (i < E) atomicAdd(&deg[dst[i]], 1);
}
__global__ void k_dis_fb(const int* __restrict__ deg, float* __restrict__ dis, int N) {
    int v = blockIdx.x * blockDim.x + threadIdx.x;
    if (v < N) dis[v] = rsqrtf((float)(deg[v] + 1));
}
__global__ void k_lin1_fb(const float* __restrict__ x, const float* __restrict__ W1,
                          const float* __restrict__ dis, float* __restrict__ hs1,
                          float* __restrict__ agg1, int N) {
    __shared__ float w[64];
    if (threadIdx.x < 64) w[threadIdx.x] = W1[threadIdx.x];
    __syncthreads();
    int v = blockIdx.x * blockDim.x + threadIdx.x;
    if (v >= N) return;
    float4 xv = ((const float4*)x)[v];
    float d = dis[v];
#pragma unroll
    for (int j = 0; j < 16; j++) {
        float h = (xv.x * w[j] + xv.y * w[16 + j] + xv.z * w[32 + j] + xv.w * w[48 + j]) * d;
        hs1[v * 16 + j] = h;
        agg1[v * 16 + j] = h;
    }
}
__global__ void k_scat1_fb(const int* __restrict__ src, const int* __restrict__ dst,
                           const float* __restrict__ hs1, float* __restrict__ agg1, int E4) {
    int t = blockIdx.x * blockDim.x + threadIdx.x;
    if (t >= E4) return;
    int e = t >> 2, q = t & 3;
    int s = src[e], d = dst[e];
    float4 m = ((const float4*)hs1)[s * 4 + q];
    float* a = agg1 + (size_t)d * 16 + q * 4;
    atomicAdd(a + 0, m.x); atomicAdd(a + 1, m.y);
    atomicAdd(a + 2, m.z); atomicAdd(a + 3, m.w);
}
__global__ void k_lin2_fb(const float* __restrict__ agg1, const float* __restrict__ dis,
                          const float* __restrict__ b1, const float* __restrict__ W2,
                          float* __restrict__ hs2, float* __restrict__ agg2, int N) {
    __shared__ float w[32];
    __shared__ float bb[16];
    if (threadIdx.x < 32) w[threadIdx.x] = W2[threadIdx.x];
    if (threadIdx.x < 16) bb[threadIdx.x] = b1[threadIdx.x];
    __syncthreads();
    int v = blockIdx.x * blockDim.x + threadIdx.x;
    if (v >= N) return;
    float d = dis[v];
    float a0 = 0.f, a1 = 0.f;
#pragma unroll
    for (int k = 0; k < 16; k++) {
        float r = fmaxf(agg1[v * 16 + k] * d + bb[k], 0.0f);
        a0 += r * w[k * 2 + 0];
        a1 += r * w[k * 2 + 1];
    }
    float2 hv = make_float2(a0 * d, a1 * d);
    ((float2*)hs2)[v] = hv;
    ((float2*)agg2)[v] = hv;
}
__global__ void k_scat2_fb(const int* __restrict__ src, const int* __restrict__ dst,
                           const float* __restrict__ hs2, float* __restrict__ agg2, int E) {
    int e = blockIdx.x * blockDim.x + threadIdx.x;
    if (e >= E) return;
    int s = src[e], d = dst[e];
    float2 m = ((const float2*)hs2)[s];
    atomicAdd(&agg2[d * 2 + 0], m.x);
    atomicAdd(&agg2[d * 2 + 1], m.y);
}
__global__ void k_out_fb(const float* __restrict__ agg2, const float* __restrict__ dis,
                         const float* __restrict__ b2, float* __restrict__ out, int N) {
    int v = blockIdx.x * blockDim.x + threadIdx.x;
    if (v >= N) return;
    float d = dis[v];
    out[v * 2 + 0] = agg2[v * 2 + 0] * d + b2[0];
    out[v * 2 + 1] = agg2[v * 2 + 1] * d + b2[1];
}

// ---------------- launch ----------------

extern "C" void kernel_launch(void* const* d_in, const int* in_sizes, int n_in,
                              void* d_out, int out_size, void* d_ws, size_t ws_size,
                              hipStream_t stream) {
    const float* x  = (const float*)d_in[0];
    const int*   ei = (const int*)d_in[1];
    const float* W1 = (const float*)d_in[2];
    const float* b1 = (const float*)d_in[3];
    const float* W2 = (const float*)d_in[4];
    const float* b2 = (const float*)d_in[5];

    const int N = in_sizes[0] / 4;
    const int E = in_sizes[1] / 2;
    const int* src = ei;
    const int* dst = ei + E;
    float* outp = (float*)d_out;

    auto align = [](size_t v) { return (v + 255) & ~(size_t)255; };
    const int NBC = (N + CN - 1) >> CSH;              // 98
    const int SBN = (N + (1 << SB_SH) - 1) >> SB_SH;  // 391
    const int NC  = NBC * P2 * SBN;                   // h entries
    const int gN  = (N + TPB - 1) / TPB;
    const int ntiles = (E + STILE - 1) / STILE;       // 1563
    const bool src_fits = (size_t)N <= ((size_t)1 << (32 - CSH));
    const bool fx_safe = (long long)E <= (long long)N * 512;

    const int S1 = 16, S2 = 16;
    size_t part1_bytes = (size_t)NBC * S1 * CN * 16;
    size_t part2_bytes = (size_t)NBC * S2 * CN * 8;
    size_t pkA_bytes = (size_t)E * 4;                 // packed, later partial1/2
    if (part1_bytes > pkA_bytes) pkA_bytes = part1_bytes;
    if (part2_bytes > pkA_bytes) pkA_bytes = part2_bytes;

    size_t need_new = align(pkA_bytes)                   /* packed / partial1 / partial2 */
                    + align((size_t)E * 4)               /* packed2 */
                    + align((size_t)N * 16)              /* xs */
                    + align((size_t)N * 16)              /* xse */
                    + align((size_t)N * 8)               /* hs2f */
                    + align((size_t)N * 8)               /* hs2e */
                    + align((size_t)N * 4)               /* deg */
                    + align((size_t)NC * 4)              /* h */
                    + align((size_t)NBC * 4)             /* hist0 */
                    + align((size_t)NBC * 4)             /* cur */
                    + align((size_t)(NBC + 1) * 4);      /* base */

    const size_t p2s_smem = (size_t)SBN * (2 + CAP) * 4; // goff|cnt2|binbuf ~34 KB

    if (ws_size >= need_new && NBC <= NBC_MAX && SBN <= SBN_MAX && src_fits && fx_safe) {
        char* ws = (char*)d_ws;
        unsigned* packed = (unsigned*)ws;   // dead after p2scat
        u64* partial1 = (u64*)ws;           // aliased: live agg1n..comb1q
        u64* partial2 = (u64*)ws;           // aliased: live agg2n..comb2q
        ws += align(pkA_bytes);
        unsigned* packed2 = (unsigned*)ws; ws += align((size_t)E * 4);
        float* xs    = (float*)ws;    ws += align((size_t)N * 16);
        unsigned* xse = (unsigned*)ws; ws += align((size_t)N * 16);
        float* hs2f  = (float*)ws;    ws += align((size_t)N * 8);
        unsigned* hs2e = (unsigned*)ws; ws += align((size_t)N * 8);
        int* deg     = (int*)ws;      ws += align((size_t)N * 4);
        int* h       = (int*)ws;      ws += align((size_t)NC * 4);
        int* hist0   = (int*)ws;      ws += align((size_t)NBC * 4);
        int* cur     = (int*)ws;      ws += align((size_t)NBC * 4);
        int* base    = (int*)ws;      ws += align((size_t)(NBC + 1) * 4);

        k_zero2<<<gN, TPB, 0, stream>>>(deg, N, hist0, NBC);
        k_hist0<<<1024, TPB, 0, stream>>>(dst, hist0, NBC, E);
        k_scanbase<<<1, TPB, 0, stream>>>(hist0, base, cur, NBC);
        k_bscat<<<ntiles, TPB, 0, stream>>>(src, dst, cur, packed, E, NBC);
        k_p2hist<<<NBC * P2, TPB, 0, stream>>>(packed, base, h, deg, SBN, N);
        k_scan3<<<NBC, TPB, 0, stream>>>(h, base, SBN);
        k_p2scat<<<NBC * P2, TPB, p2s_smem, stream>>>(packed, base, h, packed2, SBN);
        k_prepv<<<gN, TPB, 0, stream>>>(x, deg, xs, xse, N);
        k_agg1n<<<NBC * S1, TPB, 0, stream>>>(packed2, base, xse, partial1, S1);
        k_comb1q<<<gN, TPB, 0, stream>>>(partial1, xs, deg, W1, b1, W2, hs2f, hs2e, S1, N);
        k_agg2n<<<NBC * S2, TPB, 0, stream>>>(packed2, base, hs2e, partial2, S2);
        k_comb2q<<<gN, TPB, 0, stream>>>(partial2, hs2f, deg, b2, outp, S2, N);
    } else {
        // fallback: R1 atomic-scatter pipeline
        char* ws = (char*)d_ws;
        int*   deg  = (int*)ws;   ws += align((size_t)N * 4);
        float* dis  = (float*)ws; ws += align((size_t)N * 4);
        float* hs1  = (float*)ws; ws += align((size_t)N * 16 * 4);
        float* agg1 = (float*)ws; ws += align((size_t)N * 16 * 4);
        float* hs2  = (float*)ws; ws += align((size_t)N * 2 * 4);
        float* agg2 = (float*)ws; ws += align((size_t)N * 2 * 4);
        int gE = (E + TPB - 1) / TPB;
        int gE4 = ((size_t)E * 4 + TPB - 1) / TPB;

        k_zero<<<gN, TPB, 0, stream>>>(deg, N);
        k_deg_fb<<<gE, TPB, 0, stream>>>(dst, deg, E);
        k_dis_fb<<<gN, TPB, 0, stream>>>(deg, dis, N);
        k_lin1_fb<<<gN, TPB, 0, stream>>>(x, W1, dis, hs1, agg1, N);
        k_scat1_fb<<<gE4, TPB, 0, stream>>>(src, dst, hs1, agg1, E * 4);
        k_lin2_fb<<<gN, TPB, 0, stream>>>(agg1, dis, b1, W2, hs2, agg2, N);
        k_scat2_fb<<<gE, TPB, 0, stream>>>(src, dst, hs2, agg2, E);
        k_out_fb<<<gN, TPB, 0, stream>>>(agg2, dis, b2, outp, N);
    }
}